// Round 1
// baseline (1079.234 us; speedup 1.0000x reference)
//
#include <hip/hip_runtime.h>
#include <hip/hip_bf16.h>

#define B_ 4
#define N_ 8192
#define KNN 16
#define BN_ (B_*N_)      // 32768
#define NPOS (BN_*KNN)   // 524288

typedef __attribute__((ext_vector_type(8))) short bf16x8;
typedef __attribute__((ext_vector_type(4))) float f32x4;

static __device__ __forceinline__ unsigned short f2bf(float f) {
  union { float f; unsigned u; } v; v.f = f;
  unsigned r = v.u + 0x7fff + ((v.u >> 16) & 1);
  return (unsigned short)(r >> 16);
}
static __device__ __forceinline__ float lk(float x) { return x >= 0.f ? x : 0.2f*x; }
static __device__ __forceinline__ unsigned pk2(float a, float b) {
  return (unsigned)f2bf(a) | ((unsigned)f2bf(b) << 16);
}

// ---------------- prep: pts4 = (x,y,z,|p|^2) ----------------
__global__ void k_prep(const float* __restrict__ xyz, float4* __restrict__ pts4) {
  int i = blockIdx.x * 256 + threadIdx.x;
  if (i >= BN_) return;
  int b = i >> 13, n = i & (N_-1);
  const float* p = xyz + b*3*N_;
  float x = p[n], y = p[N_+n], z = p[2*N_+n];
  float xx = fmaf(z, z, fmaf(y, y, x*x));
  pts4[i] = make_float4(x, y, z, xx);
}

// ---------------- convert phase-2 weights to bf16 ----------------
__global__ void k_wcvt(const float* __restrict__ w_sc, const float* __restrict__ w_a,
                       const float* __restrict__ w_b, const float* __restrict__ w_c,
                       unsigned short* __restrict__ out) {
  int i = blockIdx.x*256 + threadIdx.x;   // 49152 total
  float v;
  if (i < 16384) v = w_sc[i];
  else if (i < 24576) v = w_a[i-16384];
  else if (i < 32768) v = w_b[i-24576];
  else if (i < 49152) v = w_c[i-32768];
  else return;
  out[i] = f2bf(v);
}

// ---------------- KNN: one wave per query ----------------
// lanes 0..15 hold the sorted (ascending) top-16 distances+indices.
__global__ __launch_bounds__(256) void k_knn(const float4* __restrict__ pts4,
                                             int* __restrict__ knn) {
  __shared__ float4 cand[2048];
  const int lane = threadIdx.x & 63;
  const int wid  = threadIdx.x >> 6;
  const int q = blockIdx.x * 4 + wid;        // 0..32767
  const int b = q >> 13;
  const int n = q & (N_-1);
  const float4* __restrict__ P = pts4 + (b << 13);
  float4 me = P[n];
  float av = __builtin_inff(); int ai = 0;
  float worst = __builtin_inff();
  for (int ch = 0; ch < 4; ++ch) {
    __syncthreads();
    #pragma unroll
    for (int t = 0; t < 8; ++t)
      cand[t*256 + threadIdx.x] = P[ch*2048 + t*256 + threadIdx.x];
    __syncthreads();
    for (int it = 0; it < 32; ++it) {
      int ci = it*64 + lane;
      float4 c = cand[ci];
      float dot = fmaf(me.z, c.z, fmaf(me.y, c.y, me.x*c.x));
      float d2 = (me.w + c.w) - 2.0f*dot;
      int cid = ch*2048 + ci;
      unsigned long long m = __ballot(d2 < worst);
      while (m) {
        int src = __ffsll(m) - 1;
        m &= (m - 1);
        float v = __shfl(d2, src);
        if (v < worst) {
          int id = __shfl(cid, src);
          int p = __popcll(__ballot((lane < 16) && (av <= v)));
          float pav = __shfl_up(av, 1);
          int   pai = __shfl_up(ai, 1);
          if (lane >= p) { av = (lane == p) ? v : pav; ai = (lane == p) ? id : pai; }
          worst = __shfl(av, 15);
        }
      }
    }
  }
  if (lane < 16) knn[(q << 4) + lane] = ai;
}

// ---------------- phase-1 conv-res (fp32 VALU), writes X bf16 [pos][64] ----------------
__global__ __launch_bounds__(256) void k_p1(
    const float4* __restrict__ pts4, const int* __restrict__ knn,
    const float* __restrict__ a_w, const float* __restrict__ a_b,
    const float* __restrict__ b_w, const float* __restrict__ b_b,
    const float* __restrict__ c_w, const float* __restrict__ c_b,
    const float* __restrict__ sc_w, const float* __restrict__ sc_b,
    unsigned short* __restrict__ X) {
  __shared__ float wa[640], wb[4096], wcT[4096], wsc[640], bs[256];
  for (int t = threadIdx.x; t < 640; t += 256) { wa[t] = a_w[t]; wsc[t] = sc_w[t]; }
  for (int t = threadIdx.x; t < 4096; t += 256) {
    wb[t] = b_w[t];
    wcT[t] = c_w[(t & 63)*64 + (t >> 6)];     // wcT[i*64+o] = c_w[o][i]
  }
  if (threadIdx.x < 64) {
    bs[threadIdx.x]       = a_b[threadIdx.x];
    bs[64 + threadIdx.x]  = b_b[threadIdx.x];
    bs[128 + threadIdx.x] = c_b[threadIdx.x];
    bs[192 + threadIdx.x] = sc_b[threadIdx.x];
  }
  __syncthreads();
  int pos = blockIdx.x*256 + threadIdx.x;     // 0..524287
  int bn = pos >> 4;
  int b = bn >> 13;
  float4 cp = pts4[bn];
  int nid = knn[pos];
  float4 np = pts4[(b << 13) + nid];
  float rx = np.x - cp.x, ry = np.y - cp.y, rz = np.z - cp.z;
  float dist = sqrtf(fmaf(rz, rz, fmaf(ry, ry, rx*rx)) + 1e-12f);
  float f[10] = {cp.x, cp.y, cp.z, np.x, np.y, np.z, rx, ry, rz, dist};

  float h1[64];
  #pragma unroll
  for (int o = 0; o < 64; ++o) h1[o] = bs[o];
  #pragma unroll
  for (int i = 0; i < 10; ++i) {
    float fv = f[i];
    #pragma unroll
    for (int o = 0; o < 64; ++o) h1[o] = fmaf(wa[o*10 + i], fv, h1[o]);
  }
  #pragma unroll
  for (int o = 0; o < 64; ++o) h1[o] = lk(h1[o]);

  float ou[64];
  #pragma unroll
  for (int o = 0; o < 64; ++o) ou[o] = bs[128+o] + bs[192+o];
  #pragma unroll
  for (int i = 0; i < 10; ++i) {
    float fv = f[i];
    #pragma unroll
    for (int o = 0; o < 64; ++o) ou[o] = fmaf(wsc[o*10 + i], fv, ou[o]);
  }
  for (int i = 0; i < 64; ++i) {              // dynamic loop; arrays indexed statically
    float acc = bs[64 + i];
    #pragma unroll
    for (int j = 0; j < 64; ++j) acc = fmaf(wb[i*64 + j], h1[j], acc);
    float h2 = lk(acc);
    #pragma unroll
    for (int o = 0; o < 64; ++o) ou[o] = fmaf(wcT[i*64 + o], h2, ou[o]);
  }
  unsigned short* xp = X + (size_t)pos*64;
  #pragma unroll
  for (int g = 0; g < 8; ++g) {
    unsigned short obuf[8];
    #pragma unroll
    for (int j = 0; j < 8; ++j) obuf[j] = f2bf(ou[g*8 + j]);
    *(uint4*)(xp + g*8) = *(uint4*)obuf;
  }
}

// ---------------- max over K: XM[bn][64] ----------------
__global__ void k_xmax(const unsigned short* __restrict__ X, unsigned short* __restrict__ XM) {
  int i = blockIdx.x*256 + threadIdx.x;       // BN_*8
  if (i >= BN_*8) return;
  int bn = i >> 3, g = i & 7;
  const unsigned short* p = X + (size_t)bn*16*64 + g*8;
  float m[8];
  #pragma unroll
  for (int j = 0; j < 8; ++j) m[j] = -__builtin_inff();
  #pragma unroll
  for (int k = 0; k < 16; ++k) {
    uint4 v = *(const uint4*)(p + (size_t)k*64);
    const unsigned short* s = (const unsigned short*)&v;
    #pragma unroll
    for (int j = 0; j < 8; ++j) {
      union { unsigned u; float f; } t; t.u = ((unsigned)s[j]) << 16;
      m[j] = fmaxf(m[j], t.f);
    }
  }
  unsigned short ob[8];
  #pragma unroll
  for (int j = 0; j < 8; ++j) ob[j] = f2bf(m[j]);
  *(uint4*)(XM + (size_t)bn*64 + g*8) = *(uint4*)ob;
}

// ---------------- phase-2 fused MFMA chain + max over K ----------------
// tile = 64 positions (4 bn x 16 k); 4 waves; wave wv owns cols of bn0+wv.
__global__ __launch_bounds__(256) void k_p2(
    const unsigned short* __restrict__ X, const unsigned short* __restrict__ XM,
    const unsigned short* __restrict__ wbf,
    const float* __restrict__ sc_b, const float* __restrict__ a_b,
    const float* __restrict__ b_b, const float* __restrict__ c_b,
    float* __restrict__ out) {
  __shared__ __align__(16) unsigned short Xs[64*128];
  __shared__ __align__(16) unsigned short H1s[64*64];
  __shared__ __align__(16) unsigned short H2s[64*128];
  const int tid = threadIdx.x;
  const int lane = tid & 63, wv = tid >> 6;
  const int bn0 = blockIdx.x * 4;
  // stage X tile: rows = pos_local, 128 ch = [x(64) | x1max(64)], XOR-swizzled
  #pragma unroll
  for (int j = 0; j < 4; ++j) {
    int cc = tid + 256*j;
    int p = cc >> 4, seg = cc & 15;
    int bn = bn0 + (p >> 4), kk = p & 15;
    uint4 v;
    if (seg < 8) v = *(const uint4*)(X + ((size_t)(bn*16 + kk))*64 + seg*8);
    else         v = *(const uint4*)(XM + (size_t)bn*64 + (seg-8)*8);
    int dst = p*256 + ((seg*16) ^ ((p & 7) << 4));
    *(uint4*)((char*)Xs + dst) = v;
  }
  __syncthreads();

  const unsigned short* wsc = wbf;
  const unsigned short* wa  = wbf + 16384;
  const unsigned short* wb  = wbf + 24576;
  const unsigned short* wc  = wbf + 32768;

  const int colr = lane & 15;
  const int kq = lane >> 4;
  const int pos = wv*16 + colr;

  bf16x8 bx[4];
  #pragma unroll
  for (int ks = 0; ks < 4; ++ks) {
    int k0 = ks*32 + kq*8;
    int off = pos*256 + ((k0*2) ^ ((pos & 7) << 4));
    bx[ks] = *(const bf16x8*)((const char*)Xs + off);
  }

  f32x4 acc[8];
  #pragma unroll
  for (int mt = 0; mt < 8; ++mt) {
    int r0 = mt*16 + kq*4;
    #pragma unroll
    for (int r = 0; r < 4; ++r) acc[mt][r] = c_b[r0+r] + sc_b[r0+r];
  }
  #pragma unroll
  for (int mt = 0; mt < 8; ++mt) {
    int row = mt*16 + colr;
    #pragma unroll
    for (int ks = 0; ks < 4; ++ks) {
      bf16x8 a = *(const bf16x8*)(wsc + row*128 + ks*32 + kq*8);
      acc[mt] = __builtin_amdgcn_mfma_f32_16x16x32_bf16(a, bx[ks], acc[mt], 0, 0, 0);
    }
  }
  // GEMM a -> H1
  f32x4 ha[4];
  #pragma unroll
  for (int mt = 0; mt < 4; ++mt) {
    int r0 = mt*16 + kq*4;
    #pragma unroll
    for (int r = 0; r < 4; ++r) ha[mt][r] = a_b[r0+r];
  }
  #pragma unroll
  for (int mt = 0; mt < 4; ++mt) {
    int row = mt*16 + colr;
    #pragma unroll
    for (int ks = 0; ks < 4; ++ks) {
      bf16x8 a = *(const bf16x8*)(wa + row*128 + ks*32 + kq*8);
      ha[mt] = __builtin_amdgcn_mfma_f32_16x16x32_bf16(a, bx[ks], ha[mt], 0, 0, 0);
    }
  }
  #pragma unroll
  for (int mt = 0; mt < 4; ++mt) {
    int ch0 = mt*16 + kq*4;
    int off = pos*128 + ((ch0*2) ^ ((pos & 7) << 4));
    uint2 u; u.x = pk2(lk(ha[mt][0]), lk(ha[mt][1])); u.y = pk2(lk(ha[mt][2]), lk(ha[mt][3]));
    *(uint2*)((char*)H1s + off) = u;
  }
  __syncthreads();

  // GEMM b -> H2
  bf16x8 bh[2];
  #pragma unroll
  for (int ks = 0; ks < 2; ++ks) {
    int k0 = ks*32 + kq*8;
    int off = pos*128 + ((k0*2) ^ ((pos & 7) << 4));
    bh[ks] = *(const bf16x8*)((const char*)H1s + off);
  }
  f32x4 h2[8];
  #pragma unroll
  for (int mt = 0; mt < 8; ++mt) {
    int r0 = mt*16 + kq*4;
    #pragma unroll
    for (int r = 0; r < 4; ++r) h2[mt][r] = b_b[r0+r];
  }
  #pragma unroll
  for (int mt = 0; mt < 8; ++mt) {
    int row = mt*16 + colr;
    #pragma unroll
    for (int ks = 0; ks < 2; ++ks) {
      bf16x8 a = *(const bf16x8*)(wb + row*64 + ks*32 + kq*8);
      h2[mt] = __builtin_amdgcn_mfma_f32_16x16x32_bf16(a, bh[ks], h2[mt], 0, 0, 0);
    }
  }
  #pragma unroll
  for (int mt = 0; mt < 8; ++mt) {
    int ch0 = mt*16 + kq*4;
    int off = pos*256 + ((ch0*2) ^ ((pos & 7) << 4));
    uint2 u; u.x = pk2(lk(h2[mt][0]), lk(h2[mt][1])); u.y = pk2(lk(h2[mt][2]), lk(h2[mt][3]));
    *(uint2*)((char*)H2s + off) = u;
  }
  __syncthreads();

  // GEMM c accumulates into acc
  bf16x8 b2[4];
  #pragma unroll
  for (int ks = 0; ks < 4; ++ks) {
    int k0 = ks*32 + kq*8;
    int off = pos*256 + ((k0*2) ^ ((pos & 7) << 4));
    b2[ks] = *(const bf16x8*)((const char*)H2s + off);
  }
  #pragma unroll
  for (int mt = 0; mt < 8; ++mt) {
    int row = mt*16 + colr;
    #pragma unroll
    for (int ks = 0; ks < 4; ++ks) {
      bf16x8 a = *(const bf16x8*)(wc + row*128 + ks*32 + kq*8);
      acc[mt] = __builtin_amdgcn_mfma_f32_16x16x32_bf16(a, b2[ks], acc[mt], 0, 0, 0);
    }
  }
  // max over k (cols within each 16-lane group), store out[b][ch][n]
  int bn = bn0 + wv;
  int b = bn >> 13, n = bn & (N_-1);
  float* op = out + ((size_t)b*128)*N_ + n;
  #pragma unroll
  for (int mt = 0; mt < 8; ++mt) {
    #pragma unroll
    for (int r = 0; r < 4; ++r) {
      float v = acc[mt][r];
      v = fmaxf(v, __shfl_xor(v, 1));
      v = fmaxf(v, __shfl_xor(v, 2));
      v = fmaxf(v, __shfl_xor(v, 4));
      v = fmaxf(v, __shfl_xor(v, 8));
      if (colr == 0) op[(size_t)(mt*16 + kq*4 + r)*N_] = v;
    }
  }
}

extern "C" void kernel_launch(void* const* d_in, const int* in_sizes, int n_in,
                              void* d_out, int out_size, void* d_ws, size_t ws_size,
                              hipStream_t stream) {
  const float* xyz     = (const float*)d_in[0];
  const float* p1_sc_w = (const float*)d_in[1];
  const float* p1_sc_b = (const float*)d_in[2];
  const float* p1_a_w  = (const float*)d_in[3];
  const float* p1_a_b  = (const float*)d_in[4];
  const float* p1_b_w  = (const float*)d_in[5];
  const float* p1_b_b  = (const float*)d_in[6];
  const float* p1_c_w  = (const float*)d_in[7];
  const float* p1_c_b  = (const float*)d_in[8];
  const float* p2_sc_w = (const float*)d_in[9];
  const float* p2_sc_b = (const float*)d_in[10];
  const float* p2_a_w  = (const float*)d_in[11];
  const float* p2_a_b  = (const float*)d_in[12];
  const float* p2_b_w  = (const float*)d_in[13];
  const float* p2_b_b  = (const float*)d_in[14];
  const float* p2_c_w  = (const float*)d_in[15];
  const float* p2_c_b  = (const float*)d_in[16];

  if (ws_size < 75497472u) return;  // need ~72 MB scratch
  char* ws = (char*)d_ws;
  float4* pts4        = (float4*)(ws);
  unsigned short* wbf = (unsigned short*)(ws + 524288);
  int* knn            = (int*)(ws + 655360);
  unsigned short* X   = (unsigned short*)(ws + 4194304);
  unsigned short* XM  = (unsigned short*)(ws + 4194304 + 67108864);
  float* out = (float*)d_out;

  k_prep<<<dim3(BN_/256), dim3(256), 0, stream>>>(xyz, pts4);
  k_wcvt<<<dim3(192), dim3(256), 0, stream>>>(p2_sc_w, p2_a_w, p2_b_w, p2_c_w, wbf);
  k_knn<<<dim3(8192), dim3(256), 0, stream>>>(pts4, knn);
  k_p1<<<dim3(NPOS/256), dim3(256), 0, stream>>>(pts4, knn,
      p1_a_w, p1_a_b, p1_b_w, p1_b_b, p1_c_w, p1_c_b, p1_sc_w, p1_sc_b, X);
  k_xmax<<<dim3(BN_*8/256), dim3(256), 0, stream>>>(X, XM);
  k_p2<<<dim3(8192), dim3(256), 0, stream>>>(X, XM, wbf,
      p2_sc_b, p2_a_b, p2_b_b, p2_c_b, out);
}

// Round 2
// 763.007 us; speedup vs baseline: 1.4144x; 1.4144x over previous
//
#include <hip/hip_runtime.h>
#include <hip/hip_bf16.h>

#define B_ 4
#define N_ 8192
#define KNN 16
#define BN_ (B_*N_)      // 32768
#define NPOS (BN_*KNN)   // 524288

typedef __attribute__((ext_vector_type(8))) short bf16x8;
typedef __attribute__((ext_vector_type(4))) float f32x4;

static __device__ __forceinline__ unsigned short f2bf(float f) {
  union { float f; unsigned u; } v; v.f = f;
  unsigned r = v.u + 0x7fff + ((v.u >> 16) & 1);
  return (unsigned short)(r >> 16);
}
static __device__ __forceinline__ float lk(float x) { return x >= 0.f ? x : 0.2f*x; }
static __device__ __forceinline__ unsigned pk2(float a, float b) {
  return (unsigned)f2bf(a) | ((unsigned)f2bf(b) << 16);
}

// ---------------- prep: pts4 = (x,y,z,|p|^2) ----------------
__global__ void k_prep(const float* __restrict__ xyz, float4* __restrict__ pts4) {
  int i = blockIdx.x * 256 + threadIdx.x;
  if (i >= BN_) return;
  int b = i >> 13, n = i & (N_-1);
  const float* p = xyz + b*3*N_;
  float x = p[n], y = p[N_+n], z = p[2*N_+n];
  float xx = fmaf(z, z, fmaf(y, y, x*x));
  pts4[i] = make_float4(x, y, z, xx);
}

// ---------------- convert phase-2 weights to bf16, PRE-SWIZZLED ----------------
// LDS image byte layout per matrix: elem(row,k) at (row*K2 + 2k) ^ ((row&7)<<4).
// We store wbf so a LINEAR copy into LDS produces that image.
__global__ void k_wcvt(const float* __restrict__ w_sc, const float* __restrict__ w_a,
                       const float* __restrict__ w_b, const float* __restrict__ w_c,
                       unsigned short* __restrict__ out) {
  int i = blockIdx.x*256 + threadIdx.x;   // 49152 total bf16 elems
  if (i >= 49152) return;
  int x = i*2;                            // byte offset in the packed image
  const float* w; int base, K2;
  if (x < 32768)      { w = w_sc; base = 0;     K2 = 256; }
  else if (x < 49152) { w = w_a;  base = 32768; K2 = 256; }
  else if (x < 65536) { w = w_b;  base = 49152; K2 = 128; }
  else                { w = w_c;  base = 65536; K2 = 256; }
  int off = x - base;
  int row = off / K2;
  int colb = (off & (K2-1)) ^ ((row & 7) << 4);
  int k = colb >> 1;
  out[i] = f2bf(w[row*(K2 >> 1) + k]);
}

// ---------------- KNN: one wave per query ----------------
__global__ __launch_bounds__(256) void k_knn(const float4* __restrict__ pts4,
                                             int* __restrict__ knn) {
  __shared__ float4 cand[2048];
  const int lane = threadIdx.x & 63;
  const int wid  = threadIdx.x >> 6;
  const int q = blockIdx.x * 4 + wid;        // 0..32767
  const int b = q >> 13;
  const int n = q & (N_-1);
  const float4* __restrict__ P = pts4 + (b << 13);
  float4 me = P[n];
  float av = __builtin_inff(); int ai = 0;
  float worst = __builtin_inff();
  for (int ch = 0; ch < 4; ++ch) {
    __syncthreads();
    #pragma unroll
    for (int t = 0; t < 8; ++t)
      cand[t*256 + threadIdx.x] = P[ch*2048 + t*256 + threadIdx.x];
    __syncthreads();
    for (int it = 0; it < 32; ++it) {
      int ci = it*64 + lane;
      float4 c = cand[ci];
      float dot = fmaf(me.z, c.z, fmaf(me.y, c.y, me.x*c.x));
      float d2 = (me.w + c.w) - 2.0f*dot;
      int cid = ch*2048 + ci;
      unsigned long long m = __ballot(d2 < worst);
      while (m) {
        int src = __ffsll(m) - 1;
        m &= (m - 1);
        float v = __shfl(d2, src);
        if (v < worst) {
          int id = __shfl(cid, src);
          int p = __popcll(__ballot((lane < 16) && (av <= v)));
          float pav = __shfl_up(av, 1);
          int   pai = __shfl_up(ai, 1);
          if (lane >= p) { av = (lane == p) ? v : pav; ai = (lane == p) ? id : pai; }
          worst = __shfl(av, 15);
        }
      }
    }
  }
  if (lane < 16) knn[(q << 4) + lane] = ai;
}

// ---------------- phase-1 conv-res (fp32 VALU), writes X bf16 [pos][64] ----------------
__global__ __launch_bounds__(256) void k_p1(
    const float4* __restrict__ pts4, const int* __restrict__ knn,
    const float* __restrict__ a_w, const float* __restrict__ a_b,
    const float* __restrict__ b_w, const float* __restrict__ b_b,
    const float* __restrict__ c_w, const float* __restrict__ c_b,
    const float* __restrict__ sc_w, const float* __restrict__ sc_b,
    unsigned short* __restrict__ X) {
  __shared__ float wa[640], wb[4096], wcT[4096], wsc[640], bs[256];
  for (int t = threadIdx.x; t < 640; t += 256) { wa[t] = a_w[t]; wsc[t] = sc_w[t]; }
  for (int t = threadIdx.x; t < 4096; t += 256) {
    wb[t] = b_w[t];
    wcT[t] = c_w[(t & 63)*64 + (t >> 6)];     // wcT[i*64+o] = c_w[o][i]
  }
  if (threadIdx.x < 64) {
    bs[threadIdx.x]       = a_b[threadIdx.x];
    bs[64 + threadIdx.x]  = b_b[threadIdx.x];
    bs[128 + threadIdx.x] = c_b[threadIdx.x];
    bs[192 + threadIdx.x] = sc_b[threadIdx.x];
  }
  __syncthreads();
  int pos = blockIdx.x*256 + threadIdx.x;     // 0..524287
  int bn = pos >> 4;
  int b = bn >> 13;
  float4 cp = pts4[bn];
  int nid = knn[pos];
  float4 np = pts4[(b << 13) + nid];
  float rx = np.x - cp.x, ry = np.y - cp.y, rz = np.z - cp.z;
  float dist = sqrtf(fmaf(rz, rz, fmaf(ry, ry, rx*rx)) + 1e-12f);
  float f[10] = {cp.x, cp.y, cp.z, np.x, np.y, np.z, rx, ry, rz, dist};

  float h1[64];
  #pragma unroll
  for (int o = 0; o < 64; ++o) h1[o] = bs[o];
  #pragma unroll
  for (int i = 0; i < 10; ++i) {
    float fv = f[i];
    #pragma unroll
    for (int o = 0; o < 64; ++o) h1[o] = fmaf(wa[o*10 + i], fv, h1[o]);
  }
  #pragma unroll
  for (int o = 0; o < 64; ++o) h1[o] = lk(h1[o]);

  float ou[64];
  #pragma unroll
  for (int o = 0; o < 64; ++o) ou[o] = bs[128+o] + bs[192+o];
  #pragma unroll
  for (int i = 0; i < 10; ++i) {
    float fv = f[i];
    #pragma unroll
    for (int o = 0; o < 64; ++o) ou[o] = fmaf(wsc[o*10 + i], fv, ou[o]);
  }
  for (int i = 0; i < 64; ++i) {
    float acc = bs[64 + i];
    #pragma unroll
    for (int j = 0; j < 64; ++j) acc = fmaf(wb[i*64 + j], h1[j], acc);
    float h2 = lk(acc);
    #pragma unroll
    for (int o = 0; o < 64; ++o) ou[o] = fmaf(wcT[i*64 + o], h2, ou[o]);
  }
  unsigned short* xp = X + (size_t)pos*64;
  #pragma unroll
  for (int g = 0; g < 8; ++g) {
    unsigned short obuf[8];
    #pragma unroll
    for (int j = 0; j < 8; ++j) obuf[j] = f2bf(ou[g*8 + j]);
    *(uint4*)(xp + g*8) = *(uint4*)obuf;
  }
}

// ---------------- max over K: XM[bn][64] ----------------
__global__ void k_xmax(const unsigned short* __restrict__ X, unsigned short* __restrict__ XM) {
  int i = blockIdx.x*256 + threadIdx.x;       // BN_*8
  if (i >= BN_*8) return;
  int bn = i >> 3, g = i & 7;
  const unsigned short* p = X + (size_t)bn*16*64 + g*8;
  float m[8];
  #pragma unroll
  for (int j = 0; j < 8; ++j) m[j] = -__builtin_inff();
  #pragma unroll
  for (int k = 0; k < 16; ++k) {
    uint4 v = *(const uint4*)(p + (size_t)k*64);
    const unsigned short* s = (const unsigned short*)&v;
    #pragma unroll
    for (int j = 0; j < 8; ++j) {
      union { unsigned u; float f; } t; t.u = ((unsigned)s[j]) << 16;
      m[j] = fmaxf(m[j], t.f);
    }
  }
  unsigned short ob[8];
  #pragma unroll
  for (int j = 0; j < 8; ++j) ob[j] = f2bf(m[j]);
  *(uint4*)(XM + (size_t)bn*64 + g*8) = *(uint4*)ob;
}

// ---------------- phase-2 fused MFMA chain + max over K ----------------
// Block: 512 threads (8 waves), 256 positions (16 bn). Wave wv owns 32 positions
// = bn pair {bn0+2wv, bn0+2wv+1}, as 2 column tiles of 16. Weights staged in LDS
// once per block (pre-swizzled image -> conflict-free ds_read_b128). H1/H2
// round-trips are wave-local (no mid-chain barriers). GEMM-b pairs interleaved
// with GEMM-c k-slices so H2 needs only a 2KB double-buffered pair buffer.
__global__ __launch_bounds__(512, 2) void k_p2(
    const unsigned short* __restrict__ X, const unsigned short* __restrict__ XM,
    const unsigned short* __restrict__ wbf,
    const float* __restrict__ sc_b, const float* __restrict__ a_b,
    const float* __restrict__ b_b, const float* __restrict__ c_b,
    float* __restrict__ out) {
  __shared__ __align__(16) unsigned short Ws[49152];      // 96 KB weights
  __shared__ __align__(16) unsigned short Hr[8][2048];    // 8 x 4 KB wave regions
  __shared__ __align__(16) float outT[128][16];           // 8 KB transposed output
  const int tid = threadIdx.x;
  const int lane = tid & 63, wv = tid >> 6;
  const int colr = lane & 15, kq = lane >> 4;
  const int bn0 = blockIdx.x * 16;

  // ---- issue B-fragment global loads (each X row read by exactly one wave) ----
  bf16x8 bx[2][4];
  #pragma unroll
  for (int ct = 0; ct < 2; ++ct) {
    int bn = bn0 + wv*2 + ct;
    const unsigned short* xr = X + ((size_t)bn*16 + colr)*64 + kq*8;
    bx[ct][0] = *(const bf16x8*)(xr);
    bx[ct][1] = *(const bf16x8*)(xr + 32);
    const unsigned short* mr = XM + (size_t)bn*64 + kq*8;
    bx[ct][2] = *(const bf16x8*)(mr);
    bx[ct][3] = *(const bf16x8*)(mr + 32);
  }

  // ---- stage weights LDS (linear copy; image already swizzled) ----
  for (int it = 0; it < 12; ++it) {
    int c = it*512 + tid;                 // 6144 x 16B
    *(uint4*)((char*)Ws + c*16) = *(const uint4*)((const char*)wbf + c*16);
  }
  __syncthreads();

  const char* WSC = (const char*)Ws;              // 128x128, K2=256
  const char* WA  = (const char*)(Ws + 16384);    // 64x128,  K2=256
  const char* WB  = (const char*)(Ws + 24576);    // 128x64,  K2=128
  const char* WC  = (const char*)(Ws + 32768);    // 128x128, K2=256

#define WF(base, row, K2, ksbyte) \
  (*(const bf16x8*)((base) + (row)*(K2) + ((((ksbyte) + kq*16)) ^ (((row)&7)<<4))))

  // ---- sc GEMM (accumulates biases c_b + sc_b) ----
  f32x4 acc[8][2];
  #pragma unroll
  for (int mt = 0; mt < 8; ++mt) {
    int r0 = mt*16 + kq*4;
    #pragma unroll
    for (int r = 0; r < 4; ++r) {
      float bia = c_b[r0+r] + sc_b[r0+r];
      acc[mt][0][r] = bia; acc[mt][1][r] = bia;
    }
  }
  #pragma unroll
  for (int mt = 0; mt < 8; ++mt) {
    int row = mt*16 + colr;
    #pragma unroll
    for (int ks = 0; ks < 4; ++ks) {
      bf16x8 w = WF(WSC, row, 256, ks*64);
      acc[mt][0] = __builtin_amdgcn_mfma_f32_16x16x32_bf16(w, bx[0][ks], acc[mt][0], 0, 0, 0);
      acc[mt][1] = __builtin_amdgcn_mfma_f32_16x16x32_bf16(w, bx[1][ks], acc[mt][1], 0, 0, 0);
    }
  }

  // ---- a GEMM ----
  f32x4 ha[4][2];
  #pragma unroll
  for (int mt = 0; mt < 4; ++mt) {
    int r0 = mt*16 + kq*4;
    #pragma unroll
    for (int r = 0; r < 4; ++r) { ha[mt][0][r] = a_b[r0+r]; ha[mt][1][r] = a_b[r0+r]; }
  }
  #pragma unroll
  for (int mt = 0; mt < 4; ++mt) {
    int row = mt*16 + colr;
    #pragma unroll
    for (int ks = 0; ks < 4; ++ks) {
      bf16x8 w = WF(WA, row, 256, ks*64);
      ha[mt][0] = __builtin_amdgcn_mfma_f32_16x16x32_bf16(w, bx[0][ks], ha[mt][0], 0, 0, 0);
      ha[mt][1] = __builtin_amdgcn_mfma_f32_16x16x32_bf16(w, bx[1][ks], ha[mt][1], 0, 0, 0);
    }
  }

  // ---- leaky + write H1 (wave-local region, swizzled [pos32][64ch]) ----
  char* H = (char*)Hr[wv];
  #pragma unroll
  for (int mt = 0; mt < 4; ++mt) {
    int ch2 = (mt*16 + kq*4) * 2;
    #pragma unroll
    for (int ct = 0; ct < 2; ++ct) {
      int posl = ct*16 + colr;
      uint2 u;
      u.x = pk2(lk(ha[mt][ct][0]), lk(ha[mt][ct][1]));
      u.y = pk2(lk(ha[mt][ct][2]), lk(ha[mt][ct][3]));
      *(uint2*)(H + posl*128 + (ch2 ^ ((posl&7)<<4))) = u;
    }
  }
  // ---- read bh (full H1 into registers) ----
  bf16x8 bh[2][2];
  #pragma unroll
  for (int ct = 0; ct < 2; ++ct) {
    int posl = ct*16 + colr;
    #pragma unroll
    for (int k2 = 0; k2 < 2; ++k2)
      bh[ct][k2] = *(const bf16x8*)(H + posl*128 + ((k2*64 + kq*16) ^ ((posl&7)<<4)));
  }

  // ---- b GEMM pairs interleaved with c GEMM k-slices ----
  #pragma unroll
  for (int j = 0; j < 4; ++j) {
    f32x4 h2[2][2];   // [mtp][ct]
    #pragma unroll
    for (int mtp = 0; mtp < 2; ++mtp) {
      int r0 = (2*j + mtp)*16 + kq*4;
      #pragma unroll
      for (int r = 0; r < 4; ++r) { h2[mtp][0][r] = b_b[r0+r]; h2[mtp][1][r] = b_b[r0+r]; }
    }
    #pragma unroll
    for (int mtp = 0; mtp < 2; ++mtp) {
      int row = (2*j + mtp)*16 + colr;
      #pragma unroll
      for (int k2 = 0; k2 < 2; ++k2) {
        bf16x8 w = WF(WB, row, 128, k2*64);
        h2[mtp][0] = __builtin_amdgcn_mfma_f32_16x16x32_bf16(w, bh[0][k2], h2[mtp][0], 0, 0, 0);
        h2[mtp][1] = __builtin_amdgcn_mfma_f32_16x16x32_bf16(w, bh[1][k2], h2[mtp][1], 0, 0, 0);
      }
    }
    // write pair buffer (double-buffered 2KB halves; H1 fully consumed already)
    char* PB = H + (j & 1)*2048;
    #pragma unroll
    for (int mtp = 0; mtp < 2; ++mtp) {
      int chp2 = (mtp*16 + kq*4) * 2;
      #pragma unroll
      for (int ct = 0; ct < 2; ++ct) {
        int posl = ct*16 + colr;
        uint2 u;
        u.x = pk2(lk(h2[mtp][ct][0]), lk(h2[mtp][ct][1]));
        u.y = pk2(lk(h2[mtp][ct][2]), lk(h2[mtp][ct][3]));
        *(uint2*)(PB + posl*64 + (chp2 ^ ((posl&3)<<4))) = u;
      }
    }
    // read b2 fragments and apply c GEMM slice ks=j
    bf16x8 b2[2];
    #pragma unroll
    for (int ct = 0; ct < 2; ++ct) {
      int posl = ct*16 + colr;
      b2[ct] = *(const bf16x8*)(PB + posl*64 + ((kq*16) ^ ((posl&3)<<4)));
    }
    #pragma unroll
    for (int mt = 0; mt < 8; ++mt) {
      int row = mt*16 + colr;
      bf16x8 w = WF(WC, row, 256, j*64);
      acc[mt][0] = __builtin_amdgcn_mfma_f32_16x16x32_bf16(w, b2[0], acc[mt][0], 0, 0, 0);
      acc[mt][1] = __builtin_amdgcn_mfma_f32_16x16x32_bf16(w, b2[1], acc[mt][1], 0, 0, 0);
    }
  }
#undef WF

  // ---- max over k (16 cols of each ct tile) -> outT ----
  #pragma unroll
  for (int mt = 0; mt < 8; ++mt) {
    #pragma unroll
    for (int ct = 0; ct < 2; ++ct) {
      #pragma unroll
      for (int r = 0; r < 4; ++r) {
        float v = acc[mt][ct][r];
        v = fmaxf(v, __shfl_xor(v, 1));
        v = fmaxf(v, __shfl_xor(v, 2));
        v = fmaxf(v, __shfl_xor(v, 4));
        v = fmaxf(v, __shfl_xor(v, 8));
        if (colr == 0) outT[mt*16 + kq*4 + r][wv*2 + ct] = v;
      }
    }
  }
  __syncthreads();
  // ---- coalesced store: out[b][ch][n0..n0+15] ----
  {
    int ch = tid >> 2, p = tid & 3;
    int b = bn0 >> 13, n0 = bn0 & (N_-1);
    float4 v4 = *(const float4*)&outT[ch][p*4];
    *(float4*)(out + ((size_t)b*128 + ch)*N_ + n0 + p*4) = v4;
  }
}

extern "C" void kernel_launch(void* const* d_in, const int* in_sizes, int n_in,
                              void* d_out, int out_size, void* d_ws, size_t ws_size,
                              hipStream_t stream) {
  const float* xyz     = (const float*)d_in[0];
  const float* p1_sc_w = (const float*)d_in[1];
  const float* p1_sc_b = (const float*)d_in[2];
  const float* p1_a_w  = (const float*)d_in[3];
  const float* p1_a_b  = (const float*)d_in[4];
  const float* p1_b_w  = (const float*)d_in[5];
  const float* p1_b_b  = (const float*)d_in[6];
  const float* p1_c_w  = (const float*)d_in[7];
  const float* p1_c_b  = (const float*)d_in[8];
  const float* p2_sc_w = (const float*)d_in[9];
  const float* p2_sc_b = (const float*)d_in[10];
  const float* p2_a_w  = (const float*)d_in[11];
  const float* p2_a_b  = (const float*)d_in[12];
  const float* p2_b_w  = (const float*)d_in[13];
  const float* p2_b_b  = (const float*)d_in[14];
  const float* p2_c_w  = (const float*)d_in[15];
  const float* p2_c_b  = (const float*)d_in[16];

  if (ws_size < 75497472u) return;  // need ~72 MB scratch
  char* ws = (char*)d_ws;
  float4* pts4        = (float4*)(ws);
  unsigned short* wbf = (unsigned short*)(ws + 524288);
  int* knn            = (int*)(ws + 655360);
  unsigned short* X   = (unsigned short*)(ws + 4194304);
  unsigned short* XM  = (unsigned short*)(ws + 4194304 + 67108864);
  float* out = (float*)d_out;

  k_prep<<<dim3(BN_/256), dim3(256), 0, stream>>>(xyz, pts4);
  k_wcvt<<<dim3(192), dim3(256), 0, stream>>>(p2_sc_w, p2_a_w, p2_b_w, p2_c_w, wbf);
  k_knn<<<dim3(8192), dim3(256), 0, stream>>>(pts4, knn);
  k_p1<<<dim3(NPOS/256), dim3(256), 0, stream>>>(pts4, knn,
      p1_a_w, p1_a_b, p1_b_w, p1_b_b, p1_c_w, p1_c_b, p1_sc_w, p1_sc_b, X);
  k_xmax<<<dim3(BN_*8/256), dim3(256), 0, stream>>>(X, XM);
  k_p2<<<dim3(NPOS/256), dim3(512), 0, stream>>>(X, XM, wbf,
      p2_sc_b, p2_a_b, p2_b_b, p2_c_b, out);
}

// Round 3
// 641.763 us; speedup vs baseline: 1.6817x; 1.1889x over previous
//
#include <hip/hip_runtime.h>
#include <hip/hip_bf16.h>

#define B_ 4
#define N_ 8192
#define KNN 16
#define BN_ (B_*N_)      // 32768
#define NPOS (BN_*KNN)   // 524288

typedef __attribute__((ext_vector_type(8))) short bf16x8;
typedef __attribute__((ext_vector_type(4))) float f32x4;

static __device__ __forceinline__ unsigned short f2bf(float f) {
  union { float f; unsigned u; } v; v.f = f;
  unsigned r = v.u + 0x7fff + ((v.u >> 16) & 1);
  return (unsigned short)(r >> 16);
}
static __device__ __forceinline__ float lk(float x) { return x >= 0.f ? x : 0.2f*x; }
static __device__ __forceinline__ unsigned pk2(float a, float b) {
  return (unsigned)f2bf(a) | ((unsigned)f2bf(b) << 16);
}

// ---------------- prep: pts4 = (x,y,z,|p|^2) ----------------
__global__ void k_prep(const float* __restrict__ xyz, float4* __restrict__ pts4) {
  int i = blockIdx.x * 256 + threadIdx.x;
  if (i >= BN_) return;
  int b = i >> 13, n = i & (N_-1);
  const float* p = xyz + b*3*N_;
  float x = p[n], y = p[N_+n], z = p[2*N_+n];
  float xx = fmaf(z, z, fmaf(y, y, x*x));
  pts4[i] = make_float4(x, y, z, xx);
}

// ---------------- convert phase-2 weights to bf16, PRE-SWIZZLED ----------------
__global__ void k_wcvt(const float* __restrict__ w_sc, const float* __restrict__ w_a,
                       const float* __restrict__ w_b, const float* __restrict__ w_c,
                       unsigned short* __restrict__ out) {
  int i = blockIdx.x*256 + threadIdx.x;   // 49152 total bf16 elems
  if (i >= 49152) return;
  int x = i*2;                            // byte offset in the packed image
  const float* w; int base, K2;
  if (x < 32768)      { w = w_sc; base = 0;     K2 = 256; }
  else if (x < 49152) { w = w_a;  base = 32768; K2 = 256; }
  else if (x < 65536) { w = w_b;  base = 49152; K2 = 128; }
  else                { w = w_c;  base = 65536; K2 = 256; }
  int off = x - base;
  int row = off / K2;
  int colb = (off & (K2-1)) ^ ((row & 7) << 4);
  int k = colb >> 1;
  out[i] = f2bf(w[row*(K2 >> 1) + k]);
}

// ---------------- KNN v2: 512 thr / 8 queries per block ----------------
// One wave per query. Warm start: bitonic sort-64 of the first 64 candidates
// replaces the expensive heap-warmup inserts. Main loop screens with a stale
// (conservative) threshold; the rank-ballot inside the insert self-guards
// exactness, so `worst` is refreshed once per event-iteration only.
__global__ __launch_bounds__(512) void k_knn(const float4* __restrict__ pts4,
                                             int* __restrict__ knn) {
  __shared__ float4 cand[2048];
  const int lane = threadIdx.x & 63;
  const int wv   = threadIdx.x >> 6;
  const int q = blockIdx.x * 8 + wv;         // 0..32767
  const int b = q >> 13;
  const int n = q & (N_-1);
  const float4* __restrict__ P = pts4 + (b << 13);
  float4 me = P[n];

  float av = __builtin_inff(); int ai = 0;
  float worst = __builtin_inff();

  for (int ch = 0; ch < 4; ++ch) {
    __syncthreads();
    #pragma unroll
    for (int t = 0; t < 4; ++t)
      cand[t*512 + threadIdx.x] = P[ch*2048 + t*512 + threadIdx.x];
    __syncthreads();

    int it0 = 0;
    if (ch == 0) {
      // ---- warm start: exact top-16 of candidates 0..63 via bitonic sort ----
      float4 c = cand[lane];
      float dot = fmaf(me.z, c.z, fmaf(me.y, c.y, me.x*c.x));
      float v = (me.w + c.w) - 2.0f*dot;
      int id = lane;
      #pragma unroll
      for (int size = 2; size <= 64; size <<= 1) {
        #pragma unroll
        for (int stride = size >> 1; stride >= 1; stride >>= 1) {
          float ov = __shfl_xor(v, stride);
          int   oi = __shfl_xor(id, stride);
          bool up = ((lane & size) == 0);
          bool keepmin = (((lane & stride) == 0) == up);
          bool oless = (ov < v) || (ov == v && oi < id);
          if (oless == keepmin) { v = ov; id = oi; }
        }
      }
      av = (lane < 16) ? v : __builtin_inff();
      ai = id;
      worst = __shfl(av, 15);
      it0 = 1;
    }

    for (int it = it0; it < 32; ++it) {
      int ci = it*64 + lane;
      float4 c = cand[ci];
      float dot = fmaf(me.z, c.z, fmaf(me.y, c.y, me.x*c.x));
      float d2 = (me.w + c.w) - 2.0f*dot;
      int cid = ch*2048 + ci;
      unsigned long long m = __ballot(d2 < worst);   // stale screen: no false negatives
      if (m) {
        do {
          int src = __ffsll(m) - 1;
          m &= (m - 1);
          float v = __shfl(d2, src);
          int  id = __shfl(cid, src);
          int p = __popcll(__ballot((lane < 16) && (av <= v)));
          if (p < 16) {
            float pav = __shfl_up(av, 1);
            int   pai = __shfl_up(ai, 1);
            if (lane >= p) { av = (lane == p) ? v : pav; ai = (lane == p) ? id : pai; }
          }
        } while (m);
        worst = __shfl(av, 15);
      }
    }
  }
  if (lane < 16) knn[(q << 4) + lane] = ai;
}

// ---------------- phase-1 conv-res (fp32 VALU), writes X bf16 [pos][64] ----------------
__global__ __launch_bounds__(256) void k_p1(
    const float4* __restrict__ pts4, const int* __restrict__ knn,
    const float* __restrict__ a_w, const float* __restrict__ a_b,
    const float* __restrict__ b_w, const float* __restrict__ b_b,
    const float* __restrict__ c_w, const float* __restrict__ c_b,
    const float* __restrict__ sc_w, const float* __restrict__ sc_b,
    unsigned short* __restrict__ X) {
  __shared__ float wa[640], wb[4096], wcT[4096], wsc[640], bs[256];
  for (int t = threadIdx.x; t < 640; t += 256) { wa[t] = a_w[t]; wsc[t] = sc_w[t]; }
  for (int t = threadIdx.x; t < 4096; t += 256) {
    wb[t] = b_w[t];
    wcT[t] = c_w[(t & 63)*64 + (t >> 6)];     // wcT[i*64+o] = c_w[o][i]
  }
  if (threadIdx.x < 64) {
    bs[threadIdx.x]       = a_b[threadIdx.x];
    bs[64 + threadIdx.x]  = b_b[threadIdx.x];
    bs[128 + threadIdx.x] = c_b[threadIdx.x];
    bs[192 + threadIdx.x] = sc_b[threadIdx.x];
  }
  __syncthreads();
  int pos = blockIdx.x*256 + threadIdx.x;     // 0..524287
  int bn = pos >> 4;
  int b = bn >> 13;
  float4 cp = pts4[bn];
  int nid = knn[pos];
  float4 np = pts4[(b << 13) + nid];
  float rx = np.x - cp.x, ry = np.y - cp.y, rz = np.z - cp.z;
  float dist = sqrtf(fmaf(rz, rz, fmaf(ry, ry, rx*rx)) + 1e-12f);
  float f[10] = {cp.x, cp.y, cp.z, np.x, np.y, np.z, rx, ry, rz, dist};

  float h1[64];
  #pragma unroll
  for (int o = 0; o < 64; ++o) h1[o] = bs[o];
  #pragma unroll
  for (int i = 0; i < 10; ++i) {
    float fv = f[i];
    #pragma unroll
    for (int o = 0; o < 64; ++o) h1[o] = fmaf(wa[o*10 + i], fv, h1[o]);
  }
  #pragma unroll
  for (int o = 0; o < 64; ++o) h1[o] = lk(h1[o]);

  float ou[64];
  #pragma unroll
  for (int o = 0; o < 64; ++o) ou[o] = bs[128+o] + bs[192+o];
  #pragma unroll
  for (int i = 0; i < 10; ++i) {
    float fv = f[i];
    #pragma unroll
    for (int o = 0; o < 64; ++o) ou[o] = fmaf(wsc[o*10 + i], fv, ou[o]);
  }
  for (int i = 0; i < 64; ++i) {
    float acc = bs[64 + i];
    #pragma unroll
    for (int j = 0; j < 64; ++j) acc = fmaf(wb[i*64 + j], h1[j], acc);
    float h2 = lk(acc);
    #pragma unroll
    for (int o = 0; o < 64; ++o) ou[o] = fmaf(wcT[i*64 + o], h2, ou[o]);
  }
  unsigned short* xp = X + (size_t)pos*64;
  #pragma unroll
  for (int g = 0; g < 8; ++g) {
    unsigned short obuf[8];
    #pragma unroll
    for (int j = 0; j < 8; ++j) obuf[j] = f2bf(ou[g*8 + j]);
    *(uint4*)(xp + g*8) = *(uint4*)obuf;
  }
}

// ---------------- max over K: XM[bn][64] ----------------
__global__ void k_xmax(const unsigned short* __restrict__ X, unsigned short* __restrict__ XM) {
  int i = blockIdx.x*256 + threadIdx.x;       // BN_*8
  if (i >= BN_*8) return;
  int bn = i >> 3, g = i & 7;
  const unsigned short* p = X + (size_t)bn*16*64 + g*8;
  float m[8];
  #pragma unroll
  for (int j = 0; j < 8; ++j) m[j] = -__builtin_inff();
  #pragma unroll
  for (int k = 0; k < 16; ++k) {
    uint4 v = *(const uint4*)(p + (size_t)k*64);
    const unsigned short* s = (const unsigned short*)&v;
    #pragma unroll
    for (int j = 0; j < 8; ++j) {
      union { unsigned u; float f; } t; t.u = ((unsigned)s[j]) << 16;
      m[j] = fmaxf(m[j], t.f);
    }
  }
  unsigned short ob[8];
  #pragma unroll
  for (int j = 0; j < 8; ++j) ob[j] = f2bf(m[j]);
  *(uint4*)(XM + (size_t)bn*64 + g*8) = *(uint4*)ob;
}

// ---------------- phase-2 fused MFMA chain + max over K ----------------
__global__ __launch_bounds__(512, 2) void k_p2(
    const unsigned short* __restrict__ X, const unsigned short* __restrict__ XM,
    const unsigned short* __restrict__ wbf,
    const float* __restrict__ sc_b, const float* __restrict__ a_b,
    const float* __restrict__ b_b, const float* __restrict__ c_b,
    float* __restrict__ out) {
  __shared__ __align__(16) unsigned short Ws[49152];      // 96 KB weights
  __shared__ __align__(16) unsigned short Hr[8][2048];    // 8 x 4 KB wave regions
  __shared__ __align__(16) float outT[128][16];           // 8 KB transposed output
  const int tid = threadIdx.x;
  const int lane = tid & 63, wv = tid >> 6;
  const int colr = lane & 15, kq = lane >> 4;
  const int bn0 = blockIdx.x * 16;

  // ---- issue B-fragment global loads (each X row read by exactly one wave) ----
  bf16x8 bx[2][4];
  #pragma unroll
  for (int ct = 0; ct < 2; ++ct) {
    int bn = bn0 + wv*2 + ct;
    const unsigned short* xr = X + ((size_t)bn*16 + colr)*64 + kq*8;
    bx[ct][0] = *(const bf16x8*)(xr);
    bx[ct][1] = *(const bf16x8*)(xr + 32);
    const unsigned short* mr = XM + (size_t)bn*64 + kq*8;
    bx[ct][2] = *(const bf16x8*)(mr);
    bx[ct][3] = *(const bf16x8*)(mr + 32);
  }

  // ---- stage weights LDS (linear copy; image already swizzled) ----
  for (int it = 0; it < 12; ++it) {
    int c = it*512 + tid;                 // 6144 x 16B
    *(uint4*)((char*)Ws + c*16) = *(const uint4*)((const char*)wbf + c*16);
  }
  __syncthreads();

  const char* WSC = (const char*)Ws;              // 128x128, K2=256
  const char* WA  = (const char*)(Ws + 16384);    // 64x128,  K2=256
  const char* WB  = (const char*)(Ws + 24576);    // 128x64,  K2=128
  const char* WC  = (const char*)(Ws + 32768);    // 128x128, K2=256

#define WF(base, row, K2, ksbyte) \
  (*(const bf16x8*)((base) + (row)*(K2) + ((((ksbyte) + kq*16)) ^ (((row)&7)<<4))))

  // ---- sc GEMM (accumulates biases c_b + sc_b) ----
  f32x4 acc[8][2];
  #pragma unroll
  for (int mt = 0; mt < 8; ++mt) {
    int r0 = mt*16 + kq*4;
    #pragma unroll
    for (int r = 0; r < 4; ++r) {
      float bia = c_b[r0+r] + sc_b[r0+r];
      acc[mt][0][r] = bia; acc[mt][1][r] = bia;
    }
  }
  #pragma unroll
  for (int mt = 0; mt < 8; ++mt) {
    int row = mt*16 + colr;
    #pragma unroll
    for (int ks = 0; ks < 4; ++ks) {
      bf16x8 w = WF(WSC, row, 256, ks*64);
      acc[mt][0] = __builtin_amdgcn_mfma_f32_16x16x32_bf16(w, bx[0][ks], acc[mt][0], 0, 0, 0);
      acc[mt][1] = __builtin_amdgcn_mfma_f32_16x16x32_bf16(w, bx[1][ks], acc[mt][1], 0, 0, 0);
    }
  }

  // ---- a GEMM ----
  f32x4 ha[4][2];
  #pragma unroll
  for (int mt = 0; mt < 4; ++mt) {
    int r0 = mt*16 + kq*4;
    #pragma unroll
    for (int r = 0; r < 4; ++r) { ha[mt][0][r] = a_b[r0+r]; ha[mt][1][r] = a_b[r0+r]; }
  }
  #pragma unroll
  for (int mt = 0; mt < 4; ++mt) {
    int row = mt*16 + colr;
    #pragma unroll
    for (int ks = 0; ks < 4; ++ks) {
      bf16x8 w = WF(WA, row, 256, ks*64);
      ha[mt][0] = __builtin_amdgcn_mfma_f32_16x16x32_bf16(w, bx[0][ks], ha[mt][0], 0, 0, 0);
      ha[mt][1] = __builtin_amdgcn_mfma_f32_16x16x32_bf16(w, bx[1][ks], ha[mt][1], 0, 0, 0);
    }
  }

  // ---- leaky + write H1 (wave-local region, swizzled [pos32][64ch]) ----
  char* H = (char*)Hr[wv];
  #pragma unroll
  for (int mt = 0; mt < 4; ++mt) {
    int ch2 = (mt*16 + kq*4) * 2;
    #pragma unroll
    for (int ct = 0; ct < 2; ++ct) {
      int posl = ct*16 + colr;
      uint2 u;
      u.x = pk2(lk(ha[mt][ct][0]), lk(ha[mt][ct][1]));
      u.y = pk2(lk(ha[mt][ct][2]), lk(ha[mt][ct][3]));
      *(uint2*)(H + posl*128 + (ch2 ^ ((posl&7)<<4))) = u;
    }
  }
  // ---- read bh (full H1 into registers) ----
  bf16x8 bh[2][2];
  #pragma unroll
  for (int ct = 0; ct < 2; ++ct) {
    int posl = ct*16 + colr;
    #pragma unroll
    for (int k2 = 0; k2 < 2; ++k2)
      bh[ct][k2] = *(const bf16x8*)(H + posl*128 + ((k2*64 + kq*16) ^ ((posl&7)<<4)));
  }

  // ---- b GEMM pairs interleaved with c GEMM k-slices ----
  #pragma unroll
  for (int j = 0; j < 4; ++j) {
    f32x4 h2[2][2];   // [mtp][ct]
    #pragma unroll
    for (int mtp = 0; mtp < 2; ++mtp) {
      int r0 = (2*j + mtp)*16 + kq*4;
      #pragma unroll
      for (int r = 0; r < 4; ++r) { h2[mtp][0][r] = b_b[r0+r]; h2[mtp][1][r] = b_b[r0+r]; }
    }
    #pragma unroll
    for (int mtp = 0; mtp < 2; ++mtp) {
      int row = (2*j + mtp)*16 + colr;
      #pragma unroll
      for (int k2 = 0; k2 < 2; ++k2) {
        bf16x8 w = WF(WB, row, 128, k2*64);
        h2[mtp][0] = __builtin_amdgcn_mfma_f32_16x16x32_bf16(w, bh[0][k2], h2[mtp][0], 0, 0, 0);
        h2[mtp][1] = __builtin_amdgcn_mfma_f32_16x16x32_bf16(w, bh[1][k2], h2[mtp][1], 0, 0, 0);
      }
    }
    char* PB = H + (j & 1)*2048;
    #pragma unroll
    for (int mtp = 0; mtp < 2; ++mtp) {
      int chp2 = (mtp*16 + kq*4) * 2;
      #pragma unroll
      for (int ct = 0; ct < 2; ++ct) {
        int posl = ct*16 + colr;
        uint2 u;
        u.x = pk2(lk(h2[mtp][ct][0]), lk(h2[mtp][ct][1]));
        u.y = pk2(lk(h2[mtp][ct][2]), lk(h2[mtp][ct][3]));
        *(uint2*)(PB + posl*64 + (chp2 ^ ((posl&3)<<4))) = u;
      }
    }
    bf16x8 b2[2];
    #pragma unroll
    for (int ct = 0; ct < 2; ++ct) {
      int posl = ct*16 + colr;
      b2[ct] = *(const bf16x8*)(PB + posl*64 + ((kq*16) ^ ((posl&3)<<4)));
    }
    #pragma unroll
    for (int mt = 0; mt < 8; ++mt) {
      int row = mt*16 + colr;
      bf16x8 w = WF(WC, row, 256, j*64);
      acc[mt][0] = __builtin_amdgcn_mfma_f32_16x16x32_bf16(w, b2[0], acc[mt][0], 0, 0, 0);
      acc[mt][1] = __builtin_amdgcn_mfma_f32_16x16x32_bf16(w, b2[1], acc[mt][1], 0, 0, 0);
    }
  }
#undef WF

  // ---- max over k (16 cols of each ct tile) -> outT ----
  #pragma unroll
  for (int mt = 0; mt < 8; ++mt) {
    #pragma unroll
    for (int ct = 0; ct < 2; ++ct) {
      #pragma unroll
      for (int r = 0; r < 4; ++r) {
        float v = acc[mt][ct][r];
        v = fmaxf(v, __shfl_xor(v, 1));
        v = fmaxf(v, __shfl_xor(v, 2));
        v = fmaxf(v, __shfl_xor(v, 4));
        v = fmaxf(v, __shfl_xor(v, 8));
        if (colr == 0) outT[mt*16 + kq*4 + r][wv*2 + ct] = v;
      }
    }
  }
  __syncthreads();
  {
    int ch = tid >> 2, p = tid & 3;
    int b = bn0 >> 13, n0 = bn0 & (N_-1);
    float4 v4 = *(const float4*)&outT[ch][p*4];
    *(float4*)(out + ((size_t)b*128 + ch)*N_ + n0 + p*4) = v4;
  }
}

extern "C" void kernel_launch(void* const* d_in, const int* in_sizes, int n_in,
                              void* d_out, int out_size, void* d_ws, size_t ws_size,
                              hipStream_t stream) {
  const float* xyz     = (const float*)d_in[0];
  const float* p1_sc_w = (const float*)d_in[1];
  const float* p1_sc_b = (const float*)d_in[2];
  const float* p1_a_w  = (const float*)d_in[3];
  const float* p1_a_b  = (const float*)d_in[4];
  const float* p1_b_w  = (const float*)d_in[5];
  const float* p1_b_b  = (const float*)d_in[6];
  const float* p1_c_w  = (const float*)d_in[7];
  const float* p1_c_b  = (const float*)d_in[8];
  const float* p2_sc_w = (const float*)d_in[9];
  const float* p2_sc_b = (const float*)d_in[10];
  const float* p2_a_w  = (const float*)d_in[11];
  const float* p2_a_b  = (const float*)d_in[12];
  const float* p2_b_w  = (const float*)d_in[13];
  const float* p2_b_b  = (const float*)d_in[14];
  const float* p2_c_w  = (const float*)d_in[15];
  const float* p2_c_b  = (const float*)d_in[16];

  if (ws_size < 75497472u) return;  // need ~72 MB scratch
  char* ws = (char*)d_ws;
  float4* pts4        = (float4*)(ws);
  unsigned short* wbf = (unsigned short*)(ws + 524288);
  int* knn            = (int*)(ws + 655360);
  unsigned short* X   = (unsigned short*)(ws + 4194304);
  unsigned short* XM  = (unsigned short*)(ws + 4194304 + 67108864);
  float* out = (float*)d_out;

  k_prep<<<dim3(BN_/256), dim3(256), 0, stream>>>(xyz, pts4);
  k_wcvt<<<dim3(192), dim3(256), 0, stream>>>(p2_sc_w, p2_a_w, p2_b_w, p2_c_w, wbf);
  k_knn<<<dim3(BN_/8), dim3(512), 0, stream>>>(pts4, knn);
  k_p1<<<dim3(NPOS/256), dim3(256), 0, stream>>>(pts4, knn,
      p1_a_w, p1_a_b, p1_b_w, p1_b_b, p1_c_w, p1_c_b, p1_sc_w, p1_sc_b, X);
  k_xmax<<<dim3(BN_*8/256), dim3(256), 0, stream>>>(X, XM);
  k_p2<<<dim3(NPOS/256), dim3(512), 0, stream>>>(X, XM, wbf,
      p2_sc_b, p2_a_b, p2_b_b, p2_c_b, out);
}

// Round 4
// 429.664 us; speedup vs baseline: 2.5118x; 1.4936x over previous
//
#include <hip/hip_runtime.h>
#include <hip/hip_bf16.h>

#define B_ 4
#define N_ 8192
#define KNN 16
#define BN_ (B_*N_)      // 32768
#define NPOS (BN_*KNN)   // 524288

typedef __attribute__((ext_vector_type(8))) short bf16x8;
typedef __attribute__((ext_vector_type(4))) float f32x4;

static __device__ __forceinline__ unsigned short f2bf(float f) {
  union { float f; unsigned u; } v; v.f = f;
  unsigned r = v.u + 0x7fff + ((v.u >> 16) & 1);
  return (unsigned short)(r >> 16);
}
static __device__ __forceinline__ float lk(float x) { return x >= 0.f ? x : 0.2f*x; }
static __device__ __forceinline__ unsigned pk2(float a, float b) {
  return (unsigned)f2bf(a) | ((unsigned)f2bf(b) << 16);
}

// ---------------- prep: pts4 = (x,y,z,|p|^2) ----------------
__global__ void k_prep(const float* __restrict__ xyz, float4* __restrict__ pts4) {
  int i = blockIdx.x * 256 + threadIdx.x;
  if (i >= BN_) return;
  int b = i >> 13, n = i & (N_-1);
  const float* p = xyz + b*3*N_;
  float x = p[n], y = p[N_+n], z = p[2*N_+n];
  float xx = fmaf(z, z, fmaf(y, y, x*x));
  pts4[i] = make_float4(x, y, z, xx);
}

// ---------------- convert phase-2 weights to bf16, PRE-SWIZZLED ----------------
__global__ void k_wcvt(const float* __restrict__ w_sc, const float* __restrict__ w_a,
                       const float* __restrict__ w_b, const float* __restrict__ w_c,
                       unsigned short* __restrict__ out) {
  int i = blockIdx.x*256 + threadIdx.x;   // 49152 total bf16 elems
  if (i >= 49152) return;
  int x = i*2;                            // byte offset in the packed image
  const float* w; int base, K2;
  if (x < 32768)      { w = w_sc; base = 0;     K2 = 256; }
  else if (x < 49152) { w = w_a;  base = 32768; K2 = 256; }
  else if (x < 65536) { w = w_b;  base = 49152; K2 = 128; }
  else                { w = w_c;  base = 65536; K2 = 256; }
  int off = x - base;
  int row = off / K2;
  int colb = (off & (K2-1)) ^ ((row & 7) << 4);
  int k = colb >> 1;
  out[i] = f2bf(w[row*(K2 >> 1) + k]);
}

// ---------------- KNN v2: 512 thr / 8 queries per block ----------------
__global__ __launch_bounds__(512) void k_knn(const float4* __restrict__ pts4,
                                             int* __restrict__ knn) {
  __shared__ float4 cand[2048];
  const int lane = threadIdx.x & 63;
  const int wv   = threadIdx.x >> 6;
  const int q = blockIdx.x * 8 + wv;         // 0..32767
  const int b = q >> 13;
  const int n = q & (N_-1);
  const float4* __restrict__ P = pts4 + (b << 13);
  float4 me = P[n];

  float av = __builtin_inff(); int ai = 0;
  float worst = __builtin_inff();

  for (int ch = 0; ch < 4; ++ch) {
    __syncthreads();
    #pragma unroll
    for (int t = 0; t < 4; ++t)
      cand[t*512 + threadIdx.x] = P[ch*2048 + t*512 + threadIdx.x];
    __syncthreads();

    int it0 = 0;
    if (ch == 0) {
      // warm start: exact top-16 of candidates 0..63 via bitonic sort
      float4 c = cand[lane];
      float dot = fmaf(me.z, c.z, fmaf(me.y, c.y, me.x*c.x));
      float v = (me.w + c.w) - 2.0f*dot;
      int id = lane;
      #pragma unroll
      for (int size = 2; size <= 64; size <<= 1) {
        #pragma unroll
        for (int stride = size >> 1; stride >= 1; stride >>= 1) {
          float ov = __shfl_xor(v, stride);
          int   oi = __shfl_xor(id, stride);
          bool up = ((lane & size) == 0);
          bool keepmin = (((lane & stride) == 0) == up);
          bool oless = (ov < v) || (ov == v && oi < id);
          if (oless == keepmin) { v = ov; id = oi; }
        }
      }
      av = (lane < 16) ? v : __builtin_inff();
      ai = id;
      worst = __shfl(av, 15);
      it0 = 1;
    }

    for (int it = it0; it < 32; ++it) {
      int ci = it*64 + lane;
      float4 c = cand[ci];
      float dot = fmaf(me.z, c.z, fmaf(me.y, c.y, me.x*c.x));
      float d2 = (me.w + c.w) - 2.0f*dot;
      int cid = ch*2048 + ci;
      unsigned long long m = __ballot(d2 < worst);   // stale screen: no false negatives
      if (m) {
        do {
          int src = __ffsll(m) - 1;
          m &= (m - 1);
          float v = __shfl(d2, src);
          int  id = __shfl(cid, src);
          int p = __popcll(__ballot((lane < 16) && (av <= v)));
          if (p < 16) {
            float pav = __shfl_up(av, 1);
            int   pai = __shfl_up(ai, 1);
            if (lane >= p) { av = (lane == p) ? v : pav; ai = (lane == p) ? id : pai; }
          }
        } while (m);
        worst = __shfl(av, 15);
      }
    }
  }
  if (lane < 16) knn[(q << 4) + lane] = ai;
}

// ---------------- phase-1 conv-res on MFMA; writes X bf16 [pos][64] + XM ----------------
// Block: 512 thr / 8 waves / 256 positions (16 bn). Wave wv owns bn pair
// {bn0+2wv, bn0+2wv+1} as 2 col-tiles of 16 (cols = the 16 k-neighbors of one bn).
// Waves 0-3 compute features into swizzled LDS F; waves 4-7 stage zero-padded
// bf16 weights. Chain SC/A (K=32 padded) -> B -> C with wave-local LDS
// round-trips; epilogue folds max-over-K (k_xmax) via shfl reduce.
__global__ __launch_bounds__(512, 4) void k_p1(
    const float4* __restrict__ pts4, const int* __restrict__ knn,
    const float* __restrict__ a_w, const float* __restrict__ a_b,
    const float* __restrict__ b_w, const float* __restrict__ b_b,
    const float* __restrict__ c_w, const float* __restrict__ c_b,
    const float* __restrict__ sc_w, const float* __restrict__ sc_b,
    unsigned short* __restrict__ X, unsigned short* __restrict__ XM) {
  __shared__ __align__(16) unsigned short Ws1[12288];  // 24 KB: Wa|Wsc|Wb|Wc swizzled
  __shared__ __align__(16) unsigned short Fs[8192];    // 16 KB: 8 waves x 32 pos x 32 ch
  __shared__ __align__(16) unsigned short Hr[16384];   // 32 KB: 8 waves x 32 pos x 64 ch
  const int tid = threadIdx.x;
  const int lane = tid & 63, wv = tid >> 6;
  const int colr = lane & 15, kq = lane >> 4;
  const int bn0 = blockIdx.x * 16;

  if (tid < 256) {
    // ---- features for the block's 256 positions ----
    int bnl = tid >> 4, kk = tid & 15;
    int bn = bn0 + bnl;
    int b = bn >> 13;
    float4 cp = pts4[bn];
    int nid = knn[bn*16 + kk];
    float4 np = pts4[(b << 13) + nid];
    float rx = np.x - cp.x, ry = np.y - cp.y, rz = np.z - cp.z;
    float dist = sqrtf(fmaf(rz, rz, fmaf(ry, ry, rx*rx)) + 1e-12f);
    unsigned short row[32];
    row[0]=f2bf(cp.x); row[1]=f2bf(cp.y); row[2]=f2bf(cp.z);
    row[3]=f2bf(np.x); row[4]=f2bf(np.y); row[5]=f2bf(np.z);
    row[6]=f2bf(rx);   row[7]=f2bf(ry);   row[8]=f2bf(rz);   row[9]=f2bf(dist);
    #pragma unroll
    for (int j = 10; j < 32; ++j) row[j] = 0;
    int wvp = tid >> 5, posl = tid & 31;
    char* dst = (char*)Fs + wvp*2048 + posl*64;
    #pragma unroll
    for (int c = 0; c < 4; ++c)
      *(uint4*)(dst + ((c*16) ^ ((posl&3)<<4))) = *(const uint4*)(row + c*8);
  } else {
    // ---- stage weights: zero-padded K, XOR-swizzled ----
    int tt = tid - 256;
    for (int i = 0; i < 48; ++i) {
      int e = i*256 + tt;           // 0..12287
      float val; int byteoff;
      if (e < 2048) {               // Wa 64x32 (K2=64B rows)
        int row = e >> 5, k = e & 31;
        val = (k < 10) ? a_w[row*10 + k] : 0.f;
        byteoff = row*64 + ((2*k) ^ ((row&3)<<4));
      } else if (e < 4096) {        // Wsc 64x32
        int le = e - 2048, row = le >> 5, k = le & 31;
        val = (k < 10) ? sc_w[row*10 + k] : 0.f;
        byteoff = 4096 + row*64 + ((2*k) ^ ((row&3)<<4));
      } else if (e < 8192) {        // Wb 64x64 (K2=128B rows)
        int le = e - 4096, row = le >> 6, k = le & 63;
        val = b_w[row*64 + k];
        byteoff = 8192 + row*128 + ((2*k) ^ ((row&7)<<4));
      } else {                      // Wc 64x64
        int le = e - 8192, row = le >> 6, k = le & 63;
        val = c_w[row*64 + k];
        byteoff = 16384 + row*128 + ((2*k) ^ ((row&7)<<4));
      }
      *(unsigned short*)((char*)Ws1 + byteoff) = f2bf(val);
    }
  }
  __syncthreads();

  const char* WS = (const char*)Ws1;

  // ---- F B-fragments (K=32: one slice) ----
  bf16x8 bf[2];
  #pragma unroll
  for (int ct = 0; ct < 2; ++ct) {
    int posl = ct*16 + colr;
    bf[ct] = *(const bf16x8*)((const char*)Fs + wv*2048 + posl*64 + ((kq*16) ^ ((posl&3)<<4)));
  }

  // ---- SC GEMM (acc init c_b + sc_b) ----
  f32x4 acc[4][2];
  #pragma unroll
  for (int mt = 0; mt < 4; ++mt) {
    int r0 = mt*16 + kq*4;
    #pragma unroll
    for (int r = 0; r < 4; ++r) {
      float bia = c_b[r0+r] + sc_b[r0+r];
      acc[mt][0][r] = bia; acc[mt][1][r] = bia;
    }
  }
  #pragma unroll
  for (int mt = 0; mt < 4; ++mt) {
    int row = mt*16 + colr;
    bf16x8 w = *(const bf16x8*)(WS + 4096 + row*64 + ((kq*16) ^ ((row&3)<<4)));
    acc[mt][0] = __builtin_amdgcn_mfma_f32_16x16x32_bf16(w, bf[0], acc[mt][0], 0, 0, 0);
    acc[mt][1] = __builtin_amdgcn_mfma_f32_16x16x32_bf16(w, bf[1], acc[mt][1], 0, 0, 0);
  }

  // ---- A GEMM -> h1 ----
  f32x4 ha[4][2];
  #pragma unroll
  for (int mt = 0; mt < 4; ++mt) {
    int r0 = mt*16 + kq*4;
    #pragma unroll
    for (int r = 0; r < 4; ++r) { ha[mt][0][r] = a_b[r0+r]; ha[mt][1][r] = a_b[r0+r]; }
  }
  #pragma unroll
  for (int mt = 0; mt < 4; ++mt) {
    int row = mt*16 + colr;
    bf16x8 w = *(const bf16x8*)(WS + row*64 + ((kq*16) ^ ((row&3)<<4)));
    ha[mt][0] = __builtin_amdgcn_mfma_f32_16x16x32_bf16(w, bf[0], ha[mt][0], 0, 0, 0);
    ha[mt][1] = __builtin_amdgcn_mfma_f32_16x16x32_bf16(w, bf[1], ha[mt][1], 0, 0, 0);
  }

  // ---- leaky + write h1 (wave-local, swizzled [pos32][64ch]) ----
  char* H = (char*)Hr + wv*4096;
  #pragma unroll
  for (int mt = 0; mt < 4; ++mt) {
    int ch2 = (mt*16 + kq*4) * 2;
    #pragma unroll
    for (int ct = 0; ct < 2; ++ct) {
      int posl = ct*16 + colr;
      uint2 u;
      u.x = pk2(lk(ha[mt][ct][0]), lk(ha[mt][ct][1]));
      u.y = pk2(lk(ha[mt][ct][2]), lk(ha[mt][ct][3]));
      *(uint2*)(H + posl*128 + (ch2 ^ ((posl&7)<<4))) = u;
    }
  }
  // ---- read h1 B-fragments (K=64: 2 slices) ----
  bf16x8 bh[2][2];
  #pragma unroll
  for (int ct = 0; ct < 2; ++ct) {
    int posl = ct*16 + colr;
    #pragma unroll
    for (int k2 = 0; k2 < 2; ++k2)
      bh[ct][k2] = *(const bf16x8*)(H + posl*128 + ((k2*64 + kq*16) ^ ((posl&7)<<4)));
  }

  // ---- B GEMM pairs interleaved with C GEMM k-slices ----
  #pragma unroll
  for (int jj = 0; jj < 2; ++jj) {
    f32x4 h2[2][2];   // [mtp][ct], mt = jj*2+mtp
    #pragma unroll
    for (int mtp = 0; mtp < 2; ++mtp) {
      int r0 = (jj*2 + mtp)*16 + kq*4;
      #pragma unroll
      for (int r = 0; r < 4; ++r) { h2[mtp][0][r] = b_b[r0+r]; h2[mtp][1][r] = b_b[r0+r]; }
    }
    #pragma unroll
    for (int mtp = 0; mtp < 2; ++mtp) {
      int row = (jj*2 + mtp)*16 + colr;
      #pragma unroll
      for (int k2 = 0; k2 < 2; ++k2) {
        bf16x8 w = *(const bf16x8*)(WS + 8192 + row*128 + ((k2*64 + kq*16) ^ ((row&7)<<4)));
        h2[mtp][0] = __builtin_amdgcn_mfma_f32_16x16x32_bf16(w, bh[0][k2], h2[mtp][0], 0, 0, 0);
        h2[mtp][1] = __builtin_amdgcn_mfma_f32_16x16x32_bf16(w, bh[1][k2], h2[mtp][1], 0, 0, 0);
      }
    }
    // write h2 channels jj*32..+31 (disjoint from later reads of slice jj only)
    #pragma unroll
    for (int mtp = 0; mtp < 2; ++mtp) {
      int ch2 = ((jj*2 + mtp)*16 + kq*4) * 2;
      #pragma unroll
      for (int ct = 0; ct < 2; ++ct) {
        int posl = ct*16 + colr;
        uint2 u;
        u.x = pk2(lk(h2[mtp][ct][0]), lk(h2[mtp][ct][1]));
        u.y = pk2(lk(h2[mtp][ct][2]), lk(h2[mtp][ct][3]));
        *(uint2*)(H + posl*128 + (ch2 ^ ((posl&7)<<4))) = u;
      }
    }
    // read h2 slice jj, C GEMM into acc
    bf16x8 b2[2];
    #pragma unroll
    for (int ct = 0; ct < 2; ++ct) {
      int posl = ct*16 + colr;
      b2[ct] = *(const bf16x8*)(H + posl*128 + ((jj*64 + kq*16) ^ ((posl&7)<<4)));
    }
    #pragma unroll
    for (int mt = 0; mt < 4; ++mt) {
      int row = mt*16 + colr;
      bf16x8 w = *(const bf16x8*)(WS + 16384 + row*128 + ((jj*64 + kq*16) ^ ((row&7)<<4)));
      acc[mt][0] = __builtin_amdgcn_mfma_f32_16x16x32_bf16(w, b2[0], acc[mt][0], 0, 0, 0);
      acc[mt][1] = __builtin_amdgcn_mfma_f32_16x16x32_bf16(w, b2[1], acc[mt][1], 0, 0, 0);
    }
  }

  // ---- write X + folded max-over-K (XM) ----
  #pragma unroll
  for (int ct = 0; ct < 2; ++ct) {
    int bn = bn0 + wv*2 + ct;
    #pragma unroll
    for (int mt = 0; mt < 4; ++mt) {
      int ch0 = mt*16 + kq*4;
      uint2 u;
      u.x = pk2(acc[mt][ct][0], acc[mt][ct][1]);
      u.y = pk2(acc[mt][ct][2], acc[mt][ct][3]);
      *(uint2*)(X + ((size_t)(bn*16 + colr))*64 + ch0) = u;
      // max over the 16 k-columns (lane bits 0..3)
      float m[4];
      #pragma unroll
      for (int r = 0; r < 4; ++r) {
        float v = acc[mt][ct][r];
        v = fmaxf(v, __shfl_xor(v, 1));
        v = fmaxf(v, __shfl_xor(v, 2));
        v = fmaxf(v, __shfl_xor(v, 4));
        v = fmaxf(v, __shfl_xor(v, 8));
        m[r] = v;
      }
      if (colr == 0) {
        uint2 um; um.x = pk2(m[0], m[1]); um.y = pk2(m[2], m[3]);
        *(uint2*)(XM + (size_t)bn*64 + ch0) = um;
      }
    }
  }
}

// ---------------- phase-2 fused MFMA chain + max over K ----------------
__global__ __launch_bounds__(512, 2) void k_p2(
    const unsigned short* __restrict__ X, const unsigned short* __restrict__ XM,
    const unsigned short* __restrict__ wbf,
    const float* __restrict__ sc_b, const float* __restrict__ a_b,
    const float* __restrict__ b_b, const float* __restrict__ c_b,
    float* __restrict__ out) {
  __shared__ __align__(16) unsigned short Ws[49152];      // 96 KB weights
  __shared__ __align__(16) unsigned short Hr[8][2048];    // 8 x 4 KB wave regions
  __shared__ __align__(16) float outT[128][16];           // 8 KB transposed output
  const int tid = threadIdx.x;
  const int lane = tid & 63, wv = tid >> 6;
  const int colr = lane & 15, kq = lane >> 4;
  const int bn0 = blockIdx.x * 16;

  bf16x8 bx[2][4];
  #pragma unroll
  for (int ct = 0; ct < 2; ++ct) {
    int bn = bn0 + wv*2 + ct;
    const unsigned short* xr = X + ((size_t)bn*16 + colr)*64 + kq*8;
    bx[ct][0] = *(const bf16x8*)(xr);
    bx[ct][1] = *(const bf16x8*)(xr + 32);
    const unsigned short* mr = XM + (size_t)bn*64 + kq*8;
    bx[ct][2] = *(const bf16x8*)(mr);
    bx[ct][3] = *(const bf16x8*)(mr + 32);
  }

  for (int it = 0; it < 12; ++it) {
    int c = it*512 + tid;                 // 6144 x 16B
    *(uint4*)((char*)Ws + c*16) = *(const uint4*)((const char*)wbf + c*16);
  }
  __syncthreads();

  const char* WSC = (const char*)Ws;              // 128x128, K2=256
  const char* WA  = (const char*)(Ws + 16384);    // 64x128,  K2=256
  const char* WB  = (const char*)(Ws + 24576);    // 128x64,  K2=128
  const char* WC  = (const char*)(Ws + 32768);    // 128x128, K2=256

#define WF(base, row, K2, ksbyte) \
  (*(const bf16x8*)((base) + (row)*(K2) + ((((ksbyte) + kq*16)) ^ (((row)&7)<<4))))

  f32x4 acc[8][2];
  #pragma unroll
  for (int mt = 0; mt < 8; ++mt) {
    int r0 = mt*16 + kq*4;
    #pragma unroll
    for (int r = 0; r < 4; ++r) {
      float bia = c_b[r0+r] + sc_b[r0+r];
      acc[mt][0][r] = bia; acc[mt][1][r] = bia;
    }
  }
  #pragma unroll
  for (int mt = 0; mt < 8; ++mt) {
    int row = mt*16 + colr;
    #pragma unroll
    for (int ks = 0; ks < 4; ++ks) {
      bf16x8 w = WF(WSC, row, 256, ks*64);
      acc[mt][0] = __builtin_amdgcn_mfma_f32_16x16x32_bf16(w, bx[0][ks], acc[mt][0], 0, 0, 0);
      acc[mt][1] = __builtin_amdgcn_mfma_f32_16x16x32_bf16(w, bx[1][ks], acc[mt][1], 0, 0, 0);
    }
  }

  f32x4 ha[4][2];
  #pragma unroll
  for (int mt = 0; mt < 4; ++mt) {
    int r0 = mt*16 + kq*4;
    #pragma unroll
    for (int r = 0; r < 4; ++r) { ha[mt][0][r] = a_b[r0+r]; ha[mt][1][r] = a_b[r0+r]; }
  }
  #pragma unroll
  for (int mt = 0; mt < 4; ++mt) {
    int row = mt*16 + colr;
    #pragma unroll
    for (int ks = 0; ks < 4; ++ks) {
      bf16x8 w = WF(WA, row, 256, ks*64);
      ha[mt][0] = __builtin_amdgcn_mfma_f32_16x16x32_bf16(w, bx[0][ks], ha[mt][0], 0, 0, 0);
      ha[mt][1] = __builtin_amdgcn_mfma_f32_16x16x32_bf16(w, bx[1][ks], ha[mt][1], 0, 0, 0);
    }
  }

  char* H = (char*)Hr[wv];
  #pragma unroll
  for (int mt = 0; mt < 4; ++mt) {
    int ch2 = (mt*16 + kq*4) * 2;
    #pragma unroll
    for (int ct = 0; ct < 2; ++ct) {
      int posl = ct*16 + colr;
      uint2 u;
      u.x = pk2(lk(ha[mt][ct][0]), lk(ha[mt][ct][1]));
      u.y = pk2(lk(ha[mt][ct][2]), lk(ha[mt][ct][3]));
      *(uint2*)(H + posl*128 + (ch2 ^ ((posl&7)<<4))) = u;
    }
  }
  bf16x8 bh[2][2];
  #pragma unroll
  for (int ct = 0; ct < 2; ++ct) {
    int posl = ct*16 + colr;
    #pragma unroll
    for (int k2 = 0; k2 < 2; ++k2)
      bh[ct][k2] = *(const bf16x8*)(H + posl*128 + ((k2*64 + kq*16) ^ ((posl&7)<<4)));
  }

  #pragma unroll
  for (int j = 0; j < 4; ++j) {
    f32x4 h2[2][2];
    #pragma unroll
    for (int mtp = 0; mtp < 2; ++mtp) {
      int r0 = (2*j + mtp)*16 + kq*4;
      #pragma unroll
      for (int r = 0; r < 4; ++r) { h2[mtp][0][r] = b_b[r0+r]; h2[mtp][1][r] = b_b[r0+r]; }
    }
    #pragma unroll
    for (int mtp = 0; mtp < 2; ++mtp) {
      int row = (2*j + mtp)*16 + colr;
      #pragma unroll
      for (int k2 = 0; k2 < 2; ++k2) {
        bf16x8 w = WF(WB, row, 128, k2*64);
        h2[mtp][0] = __builtin_amdgcn_mfma_f32_16x16x32_bf16(w, bh[0][k2], h2[mtp][0], 0, 0, 0);
        h2[mtp][1] = __builtin_amdgcn_mfma_f32_16x16x32_bf16(w, bh[1][k2], h2[mtp][1], 0, 0, 0);
      }
    }
    char* PB = H + (j & 1)*2048;
    #pragma unroll
    for (int mtp = 0; mtp < 2; ++mtp) {
      int chp2 = (mtp*16 + kq*4) * 2;
      #pragma unroll
      for (int ct = 0; ct < 2; ++ct) {
        int posl = ct*16 + colr;
        uint2 u;
        u.x = pk2(lk(h2[mtp][ct][0]), lk(h2[mtp][ct][1]));
        u.y = pk2(lk(h2[mtp][ct][2]), lk(h2[mtp][ct][3]));
        *(uint2*)(PB + posl*64 + (chp2 ^ ((posl&3)<<4))) = u;
      }
    }
    bf16x8 b2[2];
    #pragma unroll
    for (int ct = 0; ct < 2; ++ct) {
      int posl = ct*16 + colr;
      b2[ct] = *(const bf16x8*)(PB + posl*64 + ((kq*16) ^ ((posl&3)<<4)));
    }
    #pragma unroll
    for (int mt = 0; mt < 8; ++mt) {
      int row = mt*16 + colr;
      bf16x8 w = WF(WC, row, 256, j*64);
      acc[mt][0] = __builtin_amdgcn_mfma_f32_16x16x32_bf16(w, b2[0], acc[mt][0], 0, 0, 0);
      acc[mt][1] = __builtin_amdgcn_mfma_f32_16x16x32_bf16(w, b2[1], acc[mt][1], 0, 0, 0);
    }
  }
#undef WF

  #pragma unroll
  for (int mt = 0; mt < 8; ++mt) {
    #pragma unroll
    for (int ct = 0; ct < 2; ++ct) {
      #pragma unroll
      for (int r = 0; r < 4; ++r) {
        float v = acc[mt][ct][r];
        v = fmaxf(v, __shfl_xor(v, 1));
        v = fmaxf(v, __shfl_xor(v, 2));
        v = fmaxf(v, __shfl_xor(v, 4));
        v = fmaxf(v, __shfl_xor(v, 8));
        if (colr == 0) outT[mt*16 + kq*4 + r][wv*2 + ct] = v;
      }
    }
  }
  __syncthreads();
  {
    int ch = tid >> 2, p = tid & 3;
    int b = bn0 >> 13, n0 = bn0 & (N_-1);
    float4 v4 = *(const float4*)&outT[ch][p*4];
    *(float4*)(out + ((size_t)b*128 + ch)*N_ + n0 + p*4) = v4;
  }
}

extern "C" void kernel_launch(void* const* d_in, const int* in_sizes, int n_in,
                              void* d_out, int out_size, void* d_ws, size_t ws_size,
                              hipStream_t stream) {
  const float* xyz     = (const float*)d_in[0];
  const float* p1_sc_w = (const float*)d_in[1];
  const float* p1_sc_b = (const float*)d_in[2];
  const float* p1_a_w  = (const float*)d_in[3];
  const float* p1_a_b  = (const float*)d_in[4];
  const float* p1_b_w  = (const float*)d_in[5];
  const float* p1_b_b  = (const float*)d_in[6];
  const float* p1_c_w  = (const float*)d_in[7];
  const float* p1_c_b  = (const float*)d_in[8];
  const float* p2_sc_w = (const float*)d_in[9];
  const float* p2_sc_b = (const float*)d_in[10];
  const float* p2_a_w  = (const float*)d_in[11];
  const float* p2_a_b  = (const float*)d_in[12];
  const float* p2_b_w  = (const float*)d_in[13];
  const float* p2_b_b  = (const float*)d_in[14];
  const float* p2_c_w  = (const float*)d_in[15];
  const float* p2_c_b  = (const float*)d_in[16];

  if (ws_size < 75497472u) return;  // need ~72 MB scratch
  char* ws = (char*)d_ws;
  float4* pts4        = (float4*)(ws);
  unsigned short* wbf = (unsigned short*)(ws + 524288);
  int* knn            = (int*)(ws + 655360);
  unsigned short* X   = (unsigned short*)(ws + 4194304);
  unsigned short* XM  = (unsigned short*)(ws + 4194304 + 67108864);
  float* out = (float*)d_out;

  k_prep<<<dim3(BN_/256), dim3(256), 0, stream>>>(xyz, pts4);
  k_wcvt<<<dim3(192), dim3(256), 0, stream>>>(p2_sc_w, p2_a_w, p2_b_w, p2_c_w, wbf);
  k_knn<<<dim3(BN_/8), dim3(512), 0, stream>>>(pts4, knn);
  k_p1<<<dim3(NPOS/256), dim3(512), 0, stream>>>(pts4, knn,
      p1_a_w, p1_a_b, p1_b_w, p1_b_b, p1_c_w, p1_c_b, p1_sc_w, p1_sc_b, X, XM);
  k_p2<<<dim3(NPOS/256), dim3(512), 0, stream>>>(X, XM, wbf,
      p2_sc_b, p2_a_b, p2_b_b, p2_c_b, out);
}

// Round 5
// 404.040 us; speedup vs baseline: 2.6711x; 1.0634x over previous
//
#include <hip/hip_runtime.h>
#include <hip/hip_bf16.h>

#define B_ 4
#define N_ 8192
#define KNN 16
#define BN_ (B_*N_)      // 32768
#define NPOS (BN_*KNN)   // 524288

typedef __attribute__((ext_vector_type(8))) short bf16x8;
typedef __attribute__((ext_vector_type(4))) float f32x4;

static __device__ __forceinline__ unsigned short f2bf(float f) {
  union { float f; unsigned u; } v; v.f = f;
  unsigned r = v.u + 0x7fff + ((v.u >> 16) & 1);
  return (unsigned short)(r >> 16);
}
static __device__ __forceinline__ float lk(float x) { return x >= 0.f ? x : 0.2f*x; }
static __device__ __forceinline__ unsigned pk2(float a, float b) {
  return (unsigned)f2bf(a) | ((unsigned)f2bf(b) << 16);
}

// ---------------- prep: pts4 = (x,y,z,|p|^2) ----------------
__global__ void k_prep(const float* __restrict__ xyz, float4* __restrict__ pts4) {
  int i = blockIdx.x * 256 + threadIdx.x;
  if (i >= BN_) return;
  int b = i >> 13, n = i & (N_-1);
  const float* p = xyz + b*3*N_;
  float x = p[n], y = p[N_+n], z = p[2*N_+n];
  float xx = fmaf(z, z, fmaf(y, y, x*x));
  pts4[i] = make_float4(x, y, z, xx);
}

// ------- convert ALL weights to bf16, PRE-SWIZZLED LDS images -------
// elems [0,49152): phase-2 image  (wsc 128x128 | wa 64x128 | wb 128x64 | wc 128x128)
// elems [49152,61440): phase-1 image (wa 64x32 | wsc 64x32 | wb 64x64 | wc 64x64), K zero-padded
__global__ void k_wcvt(const float* __restrict__ w_sc, const float* __restrict__ w_a,
                       const float* __restrict__ w_b, const float* __restrict__ w_c,
                       const float* __restrict__ p1a, const float* __restrict__ p1sc,
                       const float* __restrict__ p1b, const float* __restrict__ p1c,
                       unsigned short* __restrict__ out) {
  int i = blockIdx.x*256 + threadIdx.x;
  if (i >= 61440) return;
  if (i < 49152) {
    int x = i*2;                            // byte offset in p2 image
    const float* w; int base, K2;
    if (x < 32768)      { w = w_sc; base = 0;     K2 = 256; }
    else if (x < 49152) { w = w_a;  base = 32768; K2 = 256; }
    else if (x < 65536) { w = w_b;  base = 49152; K2 = 128; }
    else                { w = w_c;  base = 65536; K2 = 256; }
    int off = x - base;
    int row = off / K2;
    int colb = (off & (K2-1)) ^ ((row & 7) << 4);
    int k = colb >> 1;
    out[i] = f2bf(w[row*(K2 >> 1) + k]);
  } else {
    int e = i - 49152;                      // 0..12287
    float val; int byteoff;
    if (e < 2048) {               // Wa 64x32 (64B rows)
      int row = e >> 5, k = e & 31;
      val = (k < 10) ? p1a[row*10 + k] : 0.f;
      byteoff = row*64 + ((2*k) ^ ((row & 3) << 4));
    } else if (e < 4096) {        // Wsc 64x32
      int le = e - 2048, row = le >> 5, k = le & 31;
      val = (k < 10) ? p1sc[row*10 + k] : 0.f;
      byteoff = 4096 + row*64 + ((2*k) ^ ((row & 3) << 4));
    } else if (e < 8192) {        // Wb 64x64 (128B rows)
      int le = e - 4096, row = le >> 6, k = le & 63;
      val = p1b[row*64 + k];
      byteoff = 8192 + row*128 + ((2*k) ^ ((row & 7) << 4));
    } else {                      // Wc 64x64
      int le = e - 8192, row = le >> 6, k = le & 63;
      val = p1c[row*64 + k];
      byteoff = 16384 + row*128 + ((2*k) ^ ((row & 7) << 4));
    }
    out[49152 + (byteoff >> 1)] = f2bf(val);
  }
}

// ---------------- KNN: 512 thr / 8 queries per block (unchanged) ----------------
__global__ __launch_bounds__(512) void k_knn(const float4* __restrict__ pts4,
                                             int* __restrict__ knn) {
  __shared__ float4 cand[2048];
  const int lane = threadIdx.x & 63;
  const int wv   = threadIdx.x >> 6;
  const int q = blockIdx.x * 8 + wv;
  const int b = q >> 13;
  const int n = q & (N_-1);
  const float4* __restrict__ P = pts4 + (b << 13);
  float4 me = P[n];

  float av = __builtin_inff(); int ai = 0;
  float worst = __builtin_inff();

  for (int ch = 0; ch < 4; ++ch) {
    __syncthreads();
    #pragma unroll
    for (int t = 0; t < 4; ++t)
      cand[t*512 + threadIdx.x] = P[ch*2048 + t*512 + threadIdx.x];
    __syncthreads();

    int it0 = 0;
    if (ch == 0) {
      float4 c = cand[lane];
      float dot = fmaf(me.z, c.z, fmaf(me.y, c.y, me.x*c.x));
      float v = (me.w + c.w) - 2.0f*dot;
      int id = lane;
      #pragma unroll
      for (int size = 2; size <= 64; size <<= 1) {
        #pragma unroll
        for (int stride = size >> 1; stride >= 1; stride >>= 1) {
          float ov = __shfl_xor(v, stride);
          int   oi = __shfl_xor(id, stride);
          bool up = ((lane & size) == 0);
          bool keepmin = (((lane & stride) == 0) == up);
          bool oless = (ov < v) || (ov == v && oi < id);
          if (oless == keepmin) { v = ov; id = oi; }
        }
      }
      av = (lane < 16) ? v : __builtin_inff();
      ai = id;
      worst = __shfl(av, 15);
      it0 = 1;
    }

    for (int it = it0; it < 32; ++it) {
      int ci = it*64 + lane;
      float4 c = cand[ci];
      float dot = fmaf(me.z, c.z, fmaf(me.y, c.y, me.x*c.x));
      float d2 = (me.w + c.w) - 2.0f*dot;
      int cid = ch*2048 + ci;
      unsigned long long m = __ballot(d2 < worst);
      if (m) {
        do {
          int src = __ffsll(m) - 1;
          m &= (m - 1);
          float v = __shfl(d2, src);
          int  id = __shfl(cid, src);
          int p = __popcll(__ballot((lane < 16) && (av <= v)));
          if (p < 16) {
            float pav = __shfl_up(av, 1);
            int   pai = __shfl_up(ai, 1);
            if (lane >= p) { av = (lane == p) ? v : pav; ai = (lane == p) ? id : pai; }
          }
        } while (m);
        worst = __shfl(av, 15);
      }
    }
  }
  if (lane < 16) knn[(q << 4) + lane] = ai;
}

// ---------------- phase-1 conv-res on MFMA, PERSISTENT (4 tiles/block) ----------------
__global__ __launch_bounds__(512, 4) void k_p1(
    const float4* __restrict__ pts4, const int* __restrict__ knn,
    const unsigned short* __restrict__ wbf,
    const float* __restrict__ a_b, const float* __restrict__ b_b,
    const float* __restrict__ c_b, const float* __restrict__ sc_b,
    unsigned short* __restrict__ X, unsigned short* __restrict__ XM) {
  __shared__ __align__(16) unsigned short Ws1[12288];  // 24 KB swizzled weights
  __shared__ __align__(16) unsigned short Fs[8192];    // 16 KB features
  __shared__ __align__(16) unsigned short Hr[16384];   // 32 KB wave H regions
  const int tid = threadIdx.x;
  const int lane = tid & 63, wv = tid >> 6;
  const int colr = lane & 15, kq = lane >> 4;

  // stage weights ONCE (linear copy of pre-swizzled image)
  #pragma unroll
  for (int j = 0; j < 3; ++j) {
    int c = j*512 + tid;
    ((uint4*)Ws1)[c] = ((const uint4*)(wbf + 49152))[c];
  }
  const char* WS = (const char*)Ws1;
  char* H = (char*)Hr + wv*4096;

  for (int tile = 0; tile < 4; ++tile) {
    const int bn0 = (blockIdx.x*4 + tile) * 16;
    __syncthreads();   // protect Fs from previous tile's readers (also covers Ws1 on tile 0)
    if (tid < 256) {
      int bnl = tid >> 4, kk = tid & 15;
      int bn = bn0 + bnl;
      int b = bn >> 13;
      float4 cp = pts4[bn];
      int nid = knn[bn*16 + kk];
      float4 np = pts4[(b << 13) + nid];
      float rx = np.x - cp.x, ry = np.y - cp.y, rz = np.z - cp.z;
      float dist = sqrtf(fmaf(rz, rz, fmaf(ry, ry, rx*rx)) + 1e-12f);
      unsigned short row[32];
      row[0]=f2bf(cp.x); row[1]=f2bf(cp.y); row[2]=f2bf(cp.z);
      row[3]=f2bf(np.x); row[4]=f2bf(np.y); row[5]=f2bf(np.z);
      row[6]=f2bf(rx);   row[7]=f2bf(ry);   row[8]=f2bf(rz);   row[9]=f2bf(dist);
      #pragma unroll
      for (int j = 10; j < 32; ++j) row[j] = 0;
      int wvp = tid >> 5, posl = tid & 31;
      char* dst = (char*)Fs + wvp*2048 + posl*64;
      #pragma unroll
      for (int c = 0; c < 4; ++c)
        *(uint4*)(dst + ((c*16) ^ ((posl&3)<<4))) = *(const uint4*)(row + c*8);
    }
    __syncthreads();

    // F fragments
    bf16x8 bfr[2];
    #pragma unroll
    for (int ct = 0; ct < 2; ++ct) {
      int posl = ct*16 + colr;
      bfr[ct] = *(const bf16x8*)((const char*)Fs + wv*2048 + posl*64 + ((kq*16) ^ ((posl&3)<<4)));
    }

    // SC GEMM (acc init c_b + sc_b)
    f32x4 acc[4][2];
    #pragma unroll
    for (int mt = 0; mt < 4; ++mt) {
      int r0 = mt*16 + kq*4;
      #pragma unroll
      for (int r = 0; r < 4; ++r) {
        float bia = c_b[r0+r] + sc_b[r0+r];
        acc[mt][0][r] = bia; acc[mt][1][r] = bia;
      }
    }
    #pragma unroll
    for (int mt = 0; mt < 4; ++mt) {
      int row = mt*16 + colr;
      bf16x8 w = *(const bf16x8*)(WS + 4096 + row*64 + ((kq*16) ^ ((row&3)<<4)));
      acc[mt][0] = __builtin_amdgcn_mfma_f32_16x16x32_bf16(w, bfr[0], acc[mt][0], 0, 0, 0);
      acc[mt][1] = __builtin_amdgcn_mfma_f32_16x16x32_bf16(w, bfr[1], acc[mt][1], 0, 0, 0);
    }

    // A GEMM
    f32x4 ha[4][2];
    #pragma unroll
    for (int mt = 0; mt < 4; ++mt) {
      int r0 = mt*16 + kq*4;
      #pragma unroll
      for (int r = 0; r < 4; ++r) { ha[mt][0][r] = a_b[r0+r]; ha[mt][1][r] = a_b[r0+r]; }
    }
    #pragma unroll
    for (int mt = 0; mt < 4; ++mt) {
      int row = mt*16 + colr;
      bf16x8 w = *(const bf16x8*)(WS + row*64 + ((kq*16) ^ ((row&3)<<4)));
      ha[mt][0] = __builtin_amdgcn_mfma_f32_16x16x32_bf16(w, bfr[0], ha[mt][0], 0, 0, 0);
      ha[mt][1] = __builtin_amdgcn_mfma_f32_16x16x32_bf16(w, bfr[1], ha[mt][1], 0, 0, 0);
    }

    // leaky + write h1
    #pragma unroll
    for (int mt = 0; mt < 4; ++mt) {
      int ch2 = (mt*16 + kq*4) * 2;
      #pragma unroll
      for (int ct = 0; ct < 2; ++ct) {
        int posl = ct*16 + colr;
        uint2 u;
        u.x = pk2(lk(ha[mt][ct][0]), lk(ha[mt][ct][1]));
        u.y = pk2(lk(ha[mt][ct][2]), lk(ha[mt][ct][3]));
        *(uint2*)(H + posl*128 + (ch2 ^ ((posl&7)<<4))) = u;
      }
    }
    bf16x8 bh[2][2];
    #pragma unroll
    for (int ct = 0; ct < 2; ++ct) {
      int posl = ct*16 + colr;
      #pragma unroll
      for (int k2 = 0; k2 < 2; ++k2)
        bh[ct][k2] = *(const bf16x8*)(H + posl*128 + ((k2*64 + kq*16) ^ ((posl&7)<<4)));
    }

    // B pairs interleaved with C k-slices
    #pragma unroll
    for (int jj = 0; jj < 2; ++jj) {
      f32x4 h2[2][2];
      #pragma unroll
      for (int mtp = 0; mtp < 2; ++mtp) {
        int r0 = (jj*2 + mtp)*16 + kq*4;
        #pragma unroll
        for (int r = 0; r < 4; ++r) { h2[mtp][0][r] = b_b[r0+r]; h2[mtp][1][r] = b_b[r0+r]; }
      }
      #pragma unroll
      for (int mtp = 0; mtp < 2; ++mtp) {
        int row = (jj*2 + mtp)*16 + colr;
        #pragma unroll
        for (int k2 = 0; k2 < 2; ++k2) {
          bf16x8 w = *(const bf16x8*)(WS + 8192 + row*128 + ((k2*64 + kq*16) ^ ((row&7)<<4)));
          h2[mtp][0] = __builtin_amdgcn_mfma_f32_16x16x32_bf16(w, bh[0][k2], h2[mtp][0], 0, 0, 0);
          h2[mtp][1] = __builtin_amdgcn_mfma_f32_16x16x32_bf16(w, bh[1][k2], h2[mtp][1], 0, 0, 0);
        }
      }
      #pragma unroll
      for (int mtp = 0; mtp < 2; ++mtp) {
        int ch2 = ((jj*2 + mtp)*16 + kq*4) * 2;
        #pragma unroll
        for (int ct = 0; ct < 2; ++ct) {
          int posl = ct*16 + colr;
          uint2 u;
          u.x = pk2(lk(h2[mtp][ct][0]), lk(h2[mtp][ct][1]));
          u.y = pk2(lk(h2[mtp][ct][2]), lk(h2[mtp][ct][3]));
          *(uint2*)(H + posl*128 + (ch2 ^ ((posl&7)<<4))) = u;
        }
      }
      bf16x8 b2[2];
      #pragma unroll
      for (int ct = 0; ct < 2; ++ct) {
        int posl = ct*16 + colr;
        b2[ct] = *(const bf16x8*)(H + posl*128 + ((jj*64 + kq*16) ^ ((posl&7)<<4)));
      }
      #pragma unroll
      for (int mt = 0; mt < 4; ++mt) {
        int row = mt*16 + colr;
        bf16x8 w = *(const bf16x8*)(WS + 16384 + row*128 + ((jj*64 + kq*16) ^ ((row&7)<<4)));
        acc[mt][0] = __builtin_amdgcn_mfma_f32_16x16x32_bf16(w, b2[0], acc[mt][0], 0, 0, 0);
        acc[mt][1] = __builtin_amdgcn_mfma_f32_16x16x32_bf16(w, b2[1], acc[mt][1], 0, 0, 0);
      }
    }

    // write X + folded max-over-K (XM)
    #pragma unroll
    for (int ct = 0; ct < 2; ++ct) {
      int bn = bn0 + wv*2 + ct;
      #pragma unroll
      for (int mt = 0; mt < 4; ++mt) {
        int ch0 = mt*16 + kq*4;
        uint2 u;
        u.x = pk2(acc[mt][ct][0], acc[mt][ct][1]);
        u.y = pk2(acc[mt][ct][2], acc[mt][ct][3]);
        *(uint2*)(X + ((size_t)(bn*16 + colr))*64 + ch0) = u;
        float m[4];
        #pragma unroll
        for (int r = 0; r < 4; ++r) {
          float v = acc[mt][ct][r];
          v = fmaxf(v, __shfl_xor(v, 1));
          v = fmaxf(v, __shfl_xor(v, 2));
          v = fmaxf(v, __shfl_xor(v, 4));
          v = fmaxf(v, __shfl_xor(v, 8));
          m[r] = v;
        }
        if (colr == 0) {
          uint2 um; um.x = pk2(m[0], m[1]); um.y = pk2(m[2], m[3]);
          *(uint2*)(XM + (size_t)bn*64 + ch0) = um;
        }
      }
    }
  }
}

// ---------------- phase-2 fused MFMA chain, PERSISTENT (8 tiles/block) ----------------
struct P2Shared {
  unsigned short Ws[49152];
  unsigned short Hr[8][2048];
  float outT[128][16];
};

static __device__ __forceinline__ void p2_loadbx(
    bf16x8 (&dst)[2][4], const unsigned short* __restrict__ X,
    const unsigned short* __restrict__ XM, int bn0, int wv, int colr, int kq) {
  #pragma unroll
  for (int ct = 0; ct < 2; ++ct) {
    int bn = bn0 + wv*2 + ct;
    const unsigned short* xr = X + ((size_t)bn*16 + colr)*64 + kq*8;
    dst[ct][0] = *(const bf16x8*)(xr);
    dst[ct][1] = *(const bf16x8*)(xr + 32);
    const unsigned short* mr = XM + (size_t)bn*64 + kq*8;
    dst[ct][2] = *(const bf16x8*)(mr);
    dst[ct][3] = *(const bf16x8*)(mr + 32);
  }
}

__global__ __launch_bounds__(512, 2) void k_p2(
    const unsigned short* __restrict__ X, const unsigned short* __restrict__ XM,
    const unsigned short* __restrict__ wbf,
    const float* __restrict__ sc_b, const float* __restrict__ a_b,
    const float* __restrict__ b_b, const float* __restrict__ c_b,
    float* __restrict__ out) {
  __shared__ __align__(16) P2Shared S;
  const int tid = threadIdx.x;
  const int lane = tid & 63, wv = tid >> 6;
  const int colr = lane & 15, kq = lane >> 4;

  // stage 96 KB weights ONCE
  #pragma unroll
  for (int it = 0; it < 12; ++it) {
    int c = it*512 + tid;
    *(uint4*)((char*)S.Ws + c*16) = *(const uint4*)((const char*)wbf + c*16);
  }

  const char* WSC = (const char*)S.Ws;
  const char* WA  = (const char*)(S.Ws + 16384);
  const char* WB  = (const char*)(S.Ws + 24576);
  const char* WC  = (const char*)(S.Ws + 32768);
  char* H = (char*)S.Hr[wv];

#define WF(base, row, K2, ksbyte) \
  (*(const bf16x8*)((base) + (row)*(K2) + ((((ksbyte) + kq*16)) ^ (((row)&7)<<4))))

  bf16x8 bx[2][4], bxn[2][4];
  p2_loadbx(bx, X, XM, blockIdx.x*8*16, wv, colr, kq);
  __syncthreads();   // weights staged

  for (int t = 0; t < 8; ++t) {
    const int bn0 = (blockIdx.x*8 + t) * 16;

    f32x4 acc[8][2];
    #pragma unroll
    for (int mt = 0; mt < 8; ++mt) {
      int r0 = mt*16 + kq*4;
      #pragma unroll
      for (int r = 0; r < 4; ++r) {
        float bia = c_b[r0+r] + sc_b[r0+r];
        acc[mt][0][r] = bia; acc[mt][1][r] = bia;
      }
    }
    #pragma unroll
    for (int mt = 0; mt < 8; ++mt) {
      int row = mt*16 + colr;
      #pragma unroll
      for (int ks = 0; ks < 4; ++ks) {
        bf16x8 w = WF(WSC, row, 256, ks*64);
        acc[mt][0] = __builtin_amdgcn_mfma_f32_16x16x32_bf16(w, bx[0][ks], acc[mt][0], 0, 0, 0);
        acc[mt][1] = __builtin_amdgcn_mfma_f32_16x16x32_bf16(w, bx[1][ks], acc[mt][1], 0, 0, 0);
      }
    }

    f32x4 ha[4][2];
    #pragma unroll
    for (int mt = 0; mt < 4; ++mt) {
      int r0 = mt*16 + kq*4;
      #pragma unroll
      for (int r = 0; r < 4; ++r) { ha[mt][0][r] = a_b[r0+r]; ha[mt][1][r] = a_b[r0+r]; }
    }
    #pragma unroll
    for (int mt = 0; mt < 4; ++mt) {
      int row = mt*16 + colr;
      #pragma unroll
      for (int ks = 0; ks < 4; ++ks) {
        bf16x8 w = WF(WA, row, 256, ks*64);
        ha[mt][0] = __builtin_amdgcn_mfma_f32_16x16x32_bf16(w, bx[0][ks], ha[mt][0], 0, 0, 0);
        ha[mt][1] = __builtin_amdgcn_mfma_f32_16x16x32_bf16(w, bx[1][ks], ha[mt][1], 0, 0, 0);
      }
    }

    // prefetch next tile's bx (clamped; redundant on last tile)
    {
      int tn = (t < 7) ? (t + 1) : 7;
      p2_loadbx(bxn, X, XM, (blockIdx.x*8 + tn) * 16, wv, colr, kq);
    }

    #pragma unroll
    for (int mt = 0; mt < 4; ++mt) {
      int ch2 = (mt*16 + kq*4) * 2;
      #pragma unroll
      for (int ct = 0; ct < 2; ++ct) {
        int posl = ct*16 + colr;
        uint2 u;
        u.x = pk2(lk(ha[mt][ct][0]), lk(ha[mt][ct][1]));
        u.y = pk2(lk(ha[mt][ct][2]), lk(ha[mt][ct][3]));
        *(uint2*)(H + posl*128 + (ch2 ^ ((posl&7)<<4))) = u;
      }
    }
    bf16x8 bh[2][2];
    #pragma unroll
    for (int ct = 0; ct < 2; ++ct) {
      int posl = ct*16 + colr;
      #pragma unroll
      for (int k2 = 0; k2 < 2; ++k2)
        bh[ct][k2] = *(const bf16x8*)(H + posl*128 + ((k2*64 + kq*16) ^ ((posl&7)<<4)));
    }

    #pragma unroll
    for (int j = 0; j < 4; ++j) {
      f32x4 h2[2][2];
      #pragma unroll
      for (int mtp = 0; mtp < 2; ++mtp) {
        int r0 = (2*j + mtp)*16 + kq*4;
        #pragma unroll
        for (int r = 0; r < 4; ++r) { h2[mtp][0][r] = b_b[r0+r]; h2[mtp][1][r] = b_b[r0+r]; }
      }
      #pragma unroll
      for (int mtp = 0; mtp < 2; ++mtp) {
        int row = (2*j + mtp)*16 + colr;
        #pragma unroll
        for (int k2 = 0; k2 < 2; ++k2) {
          bf16x8 w = WF(WB, row, 128, k2*64);
          h2[mtp][0] = __builtin_amdgcn_mfma_f32_16x16x32_bf16(w, bh[0][k2], h2[mtp][0], 0, 0, 0);
          h2[mtp][1] = __builtin_amdgcn_mfma_f32_16x16x32_bf16(w, bh[1][k2], h2[mtp][1], 0, 0, 0);
        }
      }
      char* PB = H + (j & 1)*2048;
      #pragma unroll
      for (int mtp = 0; mtp < 2; ++mtp) {
        int chp2 = (mtp*16 + kq*4) * 2;
        #pragma unroll
        for (int ct = 0; ct < 2; ++ct) {
          int posl = ct*16 + colr;
          uint2 u;
          u.x = pk2(lk(h2[mtp][ct][0]), lk(h2[mtp][ct][1]));
          u.y = pk2(lk(h2[mtp][ct][2]), lk(h2[mtp][ct][3]));
          *(uint2*)(PB + posl*64 + (chp2 ^ ((posl&3)<<4))) = u;
        }
      }
      bf16x8 b2[2];
      #pragma unroll
      for (int ct = 0; ct < 2; ++ct) {
        int posl = ct*16 + colr;
        b2[ct] = *(const bf16x8*)(PB + posl*64 + ((kq*16) ^ ((posl&3)<<4)));
      }
      #pragma unroll
      for (int mt = 0; mt < 8; ++mt) {
        int row = mt*16 + colr;
        bf16x8 w = WF(WC, row, 256, j*64);
        acc[mt][0] = __builtin_amdgcn_mfma_f32_16x16x32_bf16(w, b2[0], acc[mt][0], 0, 0, 0);
        acc[mt][1] = __builtin_amdgcn_mfma_f32_16x16x32_bf16(w, b2[1], acc[mt][1], 0, 0, 0);
      }
    }

    __syncthreads();   // previous tile's outT readers done
    #pragma unroll
    for (int mt = 0; mt < 8; ++mt) {
      #pragma unroll
      for (int ct = 0; ct < 2; ++ct) {
        #pragma unroll
        for (int r = 0; r < 4; ++r) {
          float v = acc[mt][ct][r];
          v = fmaxf(v, __shfl_xor(v, 1));
          v = fmaxf(v, __shfl_xor(v, 2));
          v = fmaxf(v, __shfl_xor(v, 4));
          v = fmaxf(v, __shfl_xor(v, 8));
          if (colr == 0) S.outT[mt*16 + kq*4 + r][wv*2 + ct] = v;
        }
      }
    }
    __syncthreads();
    {
      int ch = tid >> 2, p = tid & 3;
      int b = bn0 >> 13, n0 = bn0 & (N_-1);
      float4 v4 = *(const float4*)&S.outT[ch][p*4];
      *(float4*)(out + ((size_t)b*128 + ch)*N_ + n0 + p*4) = v4;
    }

    // rotate prefetched fragments into place
    #pragma unroll
    for (int ct = 0; ct < 2; ++ct)
      #pragma unroll
      for (int ks = 0; ks < 4; ++ks)
        bx[ct][ks] = bxn[ct][ks];
  }
#undef WF
}

extern "C" void kernel_launch(void* const* d_in, const int* in_sizes, int n_in,
                              void* d_out, int out_size, void* d_ws, size_t ws_size,
                              hipStream_t stream) {
  const float* xyz     = (const float*)d_in[0];
  const float* p1_sc_w = (const float*)d_in[1];
  const float* p1_sc_b = (const float*)d_in[2];
  const float* p1_a_w  = (const float*)d_in[3];
  const float* p1_a_b  = (const float*)d_in[4];
  const float* p1_b_w  = (const float*)d_in[5];
  const float* p1_b_b  = (const float*)d_in[6];
  const float* p1_c_w  = (const float*)d_in[7];
  const float* p1_c_b  = (const float*)d_in[8];
  const float* p2_sc_w = (const float*)d_in[9];
  const float* p2_sc_b = (const float*)d_in[10];
  const float* p2_a_w  = (const float*)d_in[11];
  const float* p2_a_b  = (const float*)d_in[12];
  const float* p2_b_w  = (const float*)d_in[13];
  const float* p2_b_b  = (const float*)d_in[14];
  const float* p2_c_w  = (const float*)d_in[15];
  const float* p2_c_b  = (const float*)d_in[16];

  if (ws_size < 75497472u) return;  // need ~72 MB scratch
  char* ws = (char*)d_ws;
  float4* pts4        = (float4*)(ws);
  unsigned short* wbf = (unsigned short*)(ws + 524288);
  int* knn            = (int*)(ws + 655360);
  unsigned short* X   = (unsigned short*)(ws + 4194304);
  unsigned short* XM  = (unsigned short*)(ws + 4194304 + 67108864);
  float* out = (float*)d_out;

  k_prep<<<dim3(BN_/256), dim3(256), 0, stream>>>(xyz, pts4);
  k_wcvt<<<dim3(240), dim3(256), 0, stream>>>(p2_sc_w, p2_a_w, p2_b_w, p2_c_w,
      p1_a_w, p1_sc_w, p1_b_w, p1_c_w, wbf);
  k_knn<<<dim3(BN_/8), dim3(512), 0, stream>>>(pts4, knn);
  k_p1<<<dim3(512), dim3(512), 0, stream>>>(pts4, knn, wbf,
      p1_a_b, p1_b_b, p1_c_b, p1_sc_b, X, XM);
  k_p2<<<dim3(256), dim3(512), 0, stream>>>(X, XM, wbf,
      p2_sc_b, p2_a_b, p2_b_b, p2_c_b, out);
}

// Round 6
// 403.109 us; speedup vs baseline: 2.6773x; 1.0023x over previous
//
#include <hip/hip_runtime.h>
#include <hip/hip_bf16.h>

#define B_ 4
#define N_ 8192
#define KNN 16
#define BN_ (B_*N_)      // 32768
#define NPOS (BN_*KNN)   // 524288

typedef __attribute__((ext_vector_type(8))) short bf16x8;
typedef __attribute__((ext_vector_type(4))) float f32x4;

static __device__ __forceinline__ unsigned short f2bf(float f) {
  union { float f; unsigned u; } v; v.f = f;
  unsigned r = v.u + 0x7fff + ((v.u >> 16) & 1);
  return (unsigned short)(r >> 16);
}
static __device__ __forceinline__ float lk(float x) { return x >= 0.f ? x : 0.2f*x; }
static __device__ __forceinline__ unsigned pk2(float a, float b) {
  return (unsigned)f2bf(a) | ((unsigned)f2bf(b) << 16);
}

// ---------------- prep: pts4 = (x,y,z,|p|^2) ----------------
__global__ void k_prep(const float* __restrict__ xyz, float4* __restrict__ pts4) {
  int i = blockIdx.x * 256 + threadIdx.x;
  if (i >= BN_) return;
  int b = i >> 13, n = i & (N_-1);
  const float* p = xyz + b*3*N_;
  float x = p[n], y = p[N_+n], z = p[2*N_+n];
  float xx = fmaf(z, z, fmaf(y, y, x*x));
  pts4[i] = make_float4(x, y, z, xx);
}

// ------- convert ALL weights to bf16, PRE-SWIZZLED LDS images -------
__global__ void k_wcvt(const float* __restrict__ w_sc, const float* __restrict__ w_a,
                       const float* __restrict__ w_b, const float* __restrict__ w_c,
                       const float* __restrict__ p1a, const float* __restrict__ p1sc,
                       const float* __restrict__ p1b, const float* __restrict__ p1c,
                       unsigned short* __restrict__ out) {
  int i = blockIdx.x*256 + threadIdx.x;
  if (i >= 61440) return;
  if (i < 49152) {
    int x = i*2;                            // byte offset in p2 image
    const float* w; int base, K2;
    if (x < 32768)      { w = w_sc; base = 0;     K2 = 256; }
    else if (x < 49152) { w = w_a;  base = 32768; K2 = 256; }
    else if (x < 65536) { w = w_b;  base = 49152; K2 = 128; }
    else                { w = w_c;  base = 65536; K2 = 256; }
    int off = x - base;
    int row = off / K2;
    int colb = (off & (K2-1)) ^ ((row & 7) << 4);
    int k = colb >> 1;
    out[i] = f2bf(w[row*(K2 >> 1) + k]);
  } else {
    int e = i - 49152;                      // 0..12287
    float val; int byteoff;
    if (e < 2048) {               // Wa 64x32 (64B rows)
      int row = e >> 5, k = e & 31;
      val = (k < 10) ? p1a[row*10 + k] : 0.f;
      byteoff = row*64 + ((2*k) ^ ((row & 3) << 4));
    } else if (e < 4096) {        // Wsc 64x32
      int le = e - 2048, row = le >> 5, k = le & 31;
      val = (k < 10) ? p1sc[row*10 + k] : 0.f;
      byteoff = 4096 + row*64 + ((2*k) ^ ((row & 3) << 4));
    } else if (e < 8192) {        // Wb 64x64 (128B rows)
      int le = e - 4096, row = le >> 6, k = le & 63;
      val = p1b[row*64 + k];
      byteoff = 8192 + row*128 + ((2*k) ^ ((row & 7) << 4));
    } else {                      // Wc 64x64
      int le = e - 8192, row = le >> 6, k = le & 63;
      val = p1c[row*64 + k];
      byteoff = 16384 + row*128 + ((2*k) ^ ((row & 7) << 4));
    }
    out[49152 + (byteoff >> 1)] = f2bf(val);
  }
}

// ---------------- KNN v3: ballot-append + bitonic compaction ----------------
// u64 key = (f32bits(d2) << 32) | idx  (d2 >= 0) -> ascending u64 order ==
// lexicographic (d2, idx): exactly top_k's stable tie-break.
static __device__ __forceinline__ unsigned long long bitonic64(
    unsigned long long key, int lane) {
  #pragma unroll
  for (int size = 2; size <= 64; size <<= 1) {
    #pragma unroll
    for (int stride = size >> 1; stride >= 1; stride >>= 1) {
      unsigned long long ok = __shfl_xor((long long)key, stride);
      bool up = ((lane & size) == 0);
      bool keepmin = (((lane & stride) == 0) == up);
      bool oless = ok < key;
      if (oless == keepmin) key = ok;
    }
  }
  return key;
}

__global__ __launch_bounds__(512) void k_knn(const float4* __restrict__ pts4,
                                             int* __restrict__ knn) {
  __shared__ float4 cand[2048];
  __shared__ unsigned long long buf[8][112];
  const int lane = threadIdx.x & 63;
  const int wv   = threadIdx.x >> 6;
  const int q = blockIdx.x * 8 + wv;
  const int b = q >> 13;
  const int n = q & (N_-1);
  const float4* __restrict__ P = pts4 + (b << 13);
  float4 me = P[n];

  unsigned long long topk = ~0ull;   // lanes 0..15: sorted top-16 keys
  float worst = __builtin_inff();
  float rhs = __builtin_inff();      // worst - me.w
  int cnt = 0;
  unsigned long long* __restrict__ bw = buf[wv];

  for (int ch = 0; ch < 4; ++ch) {
    __syncthreads();
    #pragma unroll
    for (int t = 0; t < 4; ++t)
      cand[t*512 + threadIdx.x] = P[ch*2048 + t*512 + threadIdx.x];
    __syncthreads();

    int it0 = 0;
    if (ch == 0) {
      // warm start: exact top-16 of candidates 0..63
      float4 c = cand[lane];
      float dot = fmaf(me.z, c.z, fmaf(me.y, c.y, me.x*c.x));
      float d2 = (me.w + c.w) - 2.0f*dot;
      unsigned long long key =
        ((unsigned long long)__float_as_uint(d2) << 32) | (unsigned)lane;
      topk = bitonic64(key, lane);
      unsigned long long k15 = __shfl((long long)topk, 15);
      worst = __uint_as_float((unsigned)(k15 >> 32));
      rhs = worst - me.w;
      it0 = 1;
    }

    for (int it = it0; it < 32; ++it) {
      int ci = it*64 + lane;
      float4 c = cand[ci];
      float dot = fmaf(me.z, c.z, fmaf(me.y, c.y, me.x*c.x));
      float s = fmaf(-2.0f, dot, c.w);          // d2 = me.w + s
      unsigned long long m = __ballot(s < rhs);
      if (m) {
        int prefix = __builtin_amdgcn_mbcnt_hi((unsigned)(m >> 32),
                      __builtin_amdgcn_mbcnt_lo((unsigned)m, 0));
        if (s < rhs) {
          float d2 = me.w + s;
          bw[cnt + prefix] =
            ((unsigned long long)__float_as_uint(d2) << 32)
            | (unsigned)(ch*2048 + ci);
        }
        cnt += __popcll(m);
        if (cnt >= 48) {
          int base = 0;
          while (cnt > 0) {
            int c2 = cnt > 48 ? 48 : cnt;
            unsigned long long e = (lane < 16) ? topk
              : ((lane - 16) < c2 ? bw[base + lane - 16] : ~0ull);
            topk = bitonic64(e, lane);
            base += c2; cnt -= c2;
          }
          unsigned long long k15 = __shfl((long long)topk, 15);
          worst = __uint_as_float((unsigned)(k15 >> 32));
          rhs = worst - me.w;
        }
      }
    }
  }
  // final drain
  {
    int base = 0;
    while (cnt > 0) {
      int c2 = cnt > 48 ? 48 : cnt;
      unsigned long long e = (lane < 16) ? topk
        : ((lane - 16) < c2 ? bw[base + lane - 16] : ~0ull);
      topk = bitonic64(e, lane);
      base += c2; cnt -= c2;
    }
  }
  if (lane < 16) knn[(q << 4) + lane] = (int)(unsigned)(topk & 0xffffffffu);
}

// ---------------- phase-1 conv-res on MFMA, PERSISTENT (4 tiles/block) ----------------
__global__ __launch_bounds__(512, 4) void k_p1(
    const float4* __restrict__ pts4, const int* __restrict__ knn,
    const unsigned short* __restrict__ wbf,
    const float* __restrict__ a_b, const float* __restrict__ b_b,
    const float* __restrict__ c_b, const float* __restrict__ sc_b,
    unsigned short* __restrict__ X, unsigned short* __restrict__ XM) {
  __shared__ __align__(16) unsigned short Ws1[12288];  // 24 KB swizzled weights
  __shared__ __align__(16) unsigned short Fs[8192];    // 16 KB features
  __shared__ __align__(16) unsigned short Hr[16384];   // 32 KB wave H regions
  const int tid = threadIdx.x;
  const int lane = tid & 63, wv = tid >> 6;
  const int colr = lane & 15, kq = lane >> 4;

  #pragma unroll
  for (int j = 0; j < 3; ++j) {
    int c = j*512 + tid;
    ((uint4*)Ws1)[c] = ((const uint4*)(wbf + 49152))[c];
  }
  const char* WS = (const char*)Ws1;
  char* H = (char*)Hr + wv*4096;

  for (int tile = 0; tile < 4; ++tile) {
    const int bn0 = (blockIdx.x*4 + tile) * 16;
    __syncthreads();
    if (tid < 256) {
      int bnl = tid >> 4, kk = tid & 15;
      int bn = bn0 + bnl;
      int b = bn >> 13;
      float4 cp = pts4[bn];
      int nid = knn[bn*16 + kk];
      float4 np = pts4[(b << 13) + nid];
      float rx = np.x - cp.x, ry = np.y - cp.y, rz = np.z - cp.z;
      float dist = sqrtf(fmaf(rz, rz, fmaf(ry, ry, rx*rx)) + 1e-12f);
      unsigned short row[32];
      row[0]=f2bf(cp.x); row[1]=f2bf(cp.y); row[2]=f2bf(cp.z);
      row[3]=f2bf(np.x); row[4]=f2bf(np.y); row[5]=f2bf(np.z);
      row[6]=f2bf(rx);   row[7]=f2bf(ry);   row[8]=f2bf(rz);   row[9]=f2bf(dist);
      #pragma unroll
      for (int j = 10; j < 32; ++j) row[j] = 0;
      int wvp = tid >> 5, posl = tid & 31;
      char* dst = (char*)Fs + wvp*2048 + posl*64;
      #pragma unroll
      for (int c = 0; c < 4; ++c)
        *(uint4*)(dst + ((c*16) ^ ((posl&3)<<4))) = *(const uint4*)(row + c*8);
    }
    __syncthreads();

    bf16x8 bfr[2];
    #pragma unroll
    for (int ct = 0; ct < 2; ++ct) {
      int posl = ct*16 + colr;
      bfr[ct] = *(const bf16x8*)((const char*)Fs + wv*2048 + posl*64 + ((kq*16) ^ ((posl&3)<<4)));
    }

    f32x4 acc[4][2];
    #pragma unroll
    for (int mt = 0; mt < 4; ++mt) {
      int r0 = mt*16 + kq*4;
      #pragma unroll
      for (int r = 0; r < 4; ++r) {
        float bia = c_b[r0+r] + sc_b[r0+r];
        acc[mt][0][r] = bia; acc[mt][1][r] = bia;
      }
    }
    #pragma unroll
    for (int mt = 0; mt < 4; ++mt) {
      int row = mt*16 + colr;
      bf16x8 w = *(const bf16x8*)(WS + 4096 + row*64 + ((kq*16) ^ ((row&3)<<4)));
      acc[mt][0] = __builtin_amdgcn_mfma_f32_16x16x32_bf16(w, bfr[0], acc[mt][0], 0, 0, 0);
      acc[mt][1] = __builtin_amdgcn_mfma_f32_16x16x32_bf16(w, bfr[1], acc[mt][1], 0, 0, 0);
    }

    f32x4 ha[4][2];
    #pragma unroll
    for (int mt = 0; mt < 4; ++mt) {
      int r0 = mt*16 + kq*4;
      #pragma unroll
      for (int r = 0; r < 4; ++r) { ha[mt][0][r] = a_b[r0+r]; ha[mt][1][r] = a_b[r0+r]; }
    }
    #pragma unroll
    for (int mt = 0; mt < 4; ++mt) {
      int row = mt*16 + colr;
      bf16x8 w = *(const bf16x8*)(WS + row*64 + ((kq*16) ^ ((row&3)<<4)));
      ha[mt][0] = __builtin_amdgcn_mfma_f32_16x16x32_bf16(w, bfr[0], ha[mt][0], 0, 0, 0);
      ha[mt][1] = __builtin_amdgcn_mfma_f32_16x16x32_bf16(w, bfr[1], ha[mt][1], 0, 0, 0);
    }

    #pragma unroll
    for (int mt = 0; mt < 4; ++mt) {
      int ch2 = (mt*16 + kq*4) * 2;
      #pragma unroll
      for (int ct = 0; ct < 2; ++ct) {
        int posl = ct*16 + colr;
        uint2 u;
        u.x = pk2(lk(ha[mt][ct][0]), lk(ha[mt][ct][1]));
        u.y = pk2(lk(ha[mt][ct][2]), lk(ha[mt][ct][3]));
        *(uint2*)(H + posl*128 + (ch2 ^ ((posl&7)<<4))) = u;
      }
    }
    bf16x8 bh[2][2];
    #pragma unroll
    for (int ct = 0; ct < 2; ++ct) {
      int posl = ct*16 + colr;
      #pragma unroll
      for (int k2 = 0; k2 < 2; ++k2)
        bh[ct][k2] = *(const bf16x8*)(H + posl*128 + ((k2*64 + kq*16) ^ ((posl&7)<<4)));
    }

    #pragma unroll
    for (int jj = 0; jj < 2; ++jj) {
      f32x4 h2[2][2];
      #pragma unroll
      for (int mtp = 0; mtp < 2; ++mtp) {
        int r0 = (jj*2 + mtp)*16 + kq*4;
        #pragma unroll
        for (int r = 0; r < 4; ++r) { h2[mtp][0][r] = b_b[r0+r]; h2[mtp][1][r] = b_b[r0+r]; }
      }
      #pragma unroll
      for (int mtp = 0; mtp < 2; ++mtp) {
        int row = (jj*2 + mtp)*16 + colr;
        #pragma unroll
        for (int k2 = 0; k2 < 2; ++k2) {
          bf16x8 w = *(const bf16x8*)(WS + 8192 + row*128 + ((k2*64 + kq*16) ^ ((row&7)<<4)));
          h2[mtp][0] = __builtin_amdgcn_mfma_f32_16x16x32_bf16(w, bh[0][k2], h2[mtp][0], 0, 0, 0);
          h2[mtp][1] = __builtin_amdgcn_mfma_f32_16x16x32_bf16(w, bh[1][k2], h2[mtp][1], 0, 0, 0);
        }
      }
      #pragma unroll
      for (int mtp = 0; mtp < 2; ++mtp) {
        int ch2 = ((jj*2 + mtp)*16 + kq*4) * 2;
        #pragma unroll
        for (int ct = 0; ct < 2; ++ct) {
          int posl = ct*16 + colr;
          uint2 u;
          u.x = pk2(lk(h2[mtp][ct][0]), lk(h2[mtp][ct][1]));
          u.y = pk2(lk(h2[mtp][ct][2]), lk(h2[mtp][ct][3]));
          *(uint2*)(H + posl*128 + (ch2 ^ ((posl&7)<<4))) = u;
        }
      }
      bf16x8 b2[2];
      #pragma unroll
      for (int ct = 0; ct < 2; ++ct) {
        int posl = ct*16 + colr;
        b2[ct] = *(const bf16x8*)(H + posl*128 + ((jj*64 + kq*16) ^ ((posl&7)<<4)));
      }
      #pragma unroll
      for (int mt = 0; mt < 4; ++mt) {
        int row = mt*16 + colr;
        bf16x8 w = *(const bf16x8*)(WS + 16384 + row*128 + ((jj*64 + kq*16) ^ ((row&7)<<4)));
        acc[mt][0] = __builtin_amdgcn_mfma_f32_16x16x32_bf16(w, b2[0], acc[mt][0], 0, 0, 0);
        acc[mt][1] = __builtin_amdgcn_mfma_f32_16x16x32_bf16(w, b2[1], acc[mt][1], 0, 0, 0);
      }
    }

    #pragma unroll
    for (int ct = 0; ct < 2; ++ct) {
      int bn = bn0 + wv*2 + ct;
      #pragma unroll
      for (int mt = 0; mt < 4; ++mt) {
        int ch0 = mt*16 + kq*4;
        uint2 u;
        u.x = pk2(acc[mt][ct][0], acc[mt][ct][1]);
        u.y = pk2(acc[mt][ct][2], acc[mt][ct][3]);
        *(uint2*)(X + ((size_t)(bn*16 + colr))*64 + ch0) = u;
        float m[4];
        #pragma unroll
        for (int r = 0; r < 4; ++r) {
          float v = acc[mt][ct][r];
          v = fmaxf(v, __shfl_xor(v, 1));
          v = fmaxf(v, __shfl_xor(v, 2));
          v = fmaxf(v, __shfl_xor(v, 4));
          v = fmaxf(v, __shfl_xor(v, 8));
          m[r] = v;
        }
        if (colr == 0) {
          uint2 um; um.x = pk2(m[0], m[1]); um.y = pk2(m[2], m[3]);
          *(uint2*)(XM + (size_t)bn*64 + ch0) = um;
        }
      }
    }
  }
}

// ---------------- phase-2 fused MFMA chain, PERSISTENT (8 tiles/block) ----------------
struct P2Shared {
  unsigned short Ws[49152];
  unsigned short Hr[8][2048];
  float outT[128][16];
};

static __device__ __forceinline__ void p2_loadbx(
    bf16x8 (&dst)[2][4], const unsigned short* __restrict__ X,
    const unsigned short* __restrict__ XM, int bn0, int wv, int colr, int kq) {
  #pragma unroll
  for (int ct = 0; ct < 2; ++ct) {
    int bn = bn0 + wv*2 + ct;
    const unsigned short* xr = X + ((size_t)bn*16 + colr)*64 + kq*8;
    dst[ct][0] = *(const bf16x8*)(xr);
    dst[ct][1] = *(const bf16x8*)(xr + 32);
    const unsigned short* mr = XM + (size_t)bn*64 + kq*8;
    dst[ct][2] = *(const bf16x8*)(mr);
    dst[ct][3] = *(const bf16x8*)(mr + 32);
  }
}

__global__ __launch_bounds__(512, 2) void k_p2(
    const unsigned short* __restrict__ X, const unsigned short* __restrict__ XM,
    const unsigned short* __restrict__ wbf,
    const float* __restrict__ sc_b, const float* __restrict__ a_b,
    const float* __restrict__ b_b, const float* __restrict__ c_b,
    float* __restrict__ out) {
  __shared__ __align__(16) P2Shared S;
  const int tid = threadIdx.x;
  const int lane = tid & 63, wv = tid >> 6;
  const int colr = lane & 15, kq = lane >> 4;

  #pragma unroll
  for (int it = 0; it < 12; ++it) {
    int c = it*512 + tid;
    *(uint4*)((char*)S.Ws + c*16) = *(const uint4*)((const char*)wbf + c*16);
  }

  const char* WSC = (const char*)S.Ws;
  const char* WA  = (const char*)(S.Ws + 16384);
  const char* WB  = (const char*)(S.Ws + 24576);
  const char* WC  = (const char*)(S.Ws + 32768);
  char* H = (char*)S.Hr[wv];

#define WF(base, row, K2, ksbyte) \
  (*(const bf16x8*)((base) + (row)*(K2) + ((((ksbyte) + kq*16)) ^ (((row)&7)<<4))))

  bf16x8 bx[2][4], bxn[2][4];
  p2_loadbx(bx, X, XM, blockIdx.x*8*16, wv, colr, kq);
  __syncthreads();

  for (int t = 0; t < 8; ++t) {
    const int bn0 = (blockIdx.x*8 + t) * 16;

    f32x4 acc[8][2];
    #pragma unroll
    for (int mt = 0; mt < 8; ++mt) {
      int r0 = mt*16 + kq*4;
      #pragma unroll
      for (int r = 0; r < 4; ++r) {
        float bia = c_b[r0+r] + sc_b[r0+r];
        acc[mt][0][r] = bia; acc[mt][1][r] = bia;
      }
    }
    #pragma unroll
    for (int mt = 0; mt < 8; ++mt) {
      int row = mt*16 + colr;
      #pragma unroll
      for (int ks = 0; ks < 4; ++ks) {
        bf16x8 w = WF(WSC, row, 256, ks*64);
        acc[mt][0] = __builtin_amdgcn_mfma_f32_16x16x32_bf16(w, bx[0][ks], acc[mt][0], 0, 0, 0);
        acc[mt][1] = __builtin_amdgcn_mfma_f32_16x16x32_bf16(w, bx[1][ks], acc[mt][1], 0, 0, 0);
      }
    }

    f32x4 ha[4][2];
    #pragma unroll
    for (int mt = 0; mt < 4; ++mt) {
      int r0 = mt*16 + kq*4;
      #pragma unroll
      for (int r = 0; r < 4; ++r) { ha[mt][0][r] = a_b[r0+r]; ha[mt][1][r] = a_b[r0+r]; }
    }
    #pragma unroll
    for (int mt = 0; mt < 4; ++mt) {
      int row = mt*16 + colr;
      #pragma unroll
      for (int ks = 0; ks < 4; ++ks) {
        bf16x8 w = WF(WA, row, 256, ks*64);
        ha[mt][0] = __builtin_amdgcn_mfma_f32_16x16x32_bf16(w, bx[0][ks], ha[mt][0], 0, 0, 0);
        ha[mt][1] = __builtin_amdgcn_mfma_f32_16x16x32_bf16(w, bx[1][ks], ha[mt][1], 0, 0, 0);
      }
    }

    {
      int tn = (t < 7) ? (t + 1) : 7;
      p2_loadbx(bxn, X, XM, (blockIdx.x*8 + tn) * 16, wv, colr, kq);
    }

    #pragma unroll
    for (int mt = 0; mt < 4; ++mt) {
      int ch2 = (mt*16 + kq*4) * 2;
      #pragma unroll
      for (int ct = 0; ct < 2; ++ct) {
        int posl = ct*16 + colr;
        uint2 u;
        u.x = pk2(lk(ha[mt][ct][0]), lk(ha[mt][ct][1]));
        u.y = pk2(lk(ha[mt][ct][2]), lk(ha[mt][ct][3]));
        *(uint2*)(H + posl*128 + (ch2 ^ ((posl&7)<<4))) = u;
      }
    }
    bf16x8 bh[2][2];
    #pragma unroll
    for (int ct = 0; ct < 2; ++ct) {
      int posl = ct*16 + colr;
      #pragma unroll
      for (int k2 = 0; k2 < 2; ++k2)
        bh[ct][k2] = *(const bf16x8*)(H + posl*128 + ((k2*64 + kq*16) ^ ((posl&7)<<4)));
    }

    #pragma unroll
    for (int j = 0; j < 4; ++j) {
      f32x4 h2[2][2];
      #pragma unroll
      for (int mtp = 0; mtp < 2; ++mtp) {
        int r0 = (2*j + mtp)*16 + kq*4;
        #pragma unroll
        for (int r = 0; r < 4; ++r) { h2[mtp][0][r] = b_b[r0+r]; h2[mtp][1][r] = b_b[r0+r]; }
      }
      #pragma unroll
      for (int mtp = 0; mtp < 2; ++mtp) {
        int row = (2*j + mtp)*16 + colr;
        #pragma unroll
        for (int k2 = 0; k2 < 2; ++k2) {
          bf16x8 w = WF(WB, row, 128, k2*64);
          h2[mtp][0] = __builtin_amdgcn_mfma_f32_16x16x32_bf16(w, bh[0][k2], h2[mtp][0], 0, 0, 0);
          h2[mtp][1] = __builtin_amdgcn_mfma_f32_16x16x32_bf16(w, bh[1][k2], h2[mtp][1], 0, 0, 0);
        }
      }
      char* PB = H + (j & 1)*2048;
      #pragma unroll
      for (int mtp = 0; mtp < 2; ++mtp) {
        int chp2 = (mtp*16 + kq*4) * 2;
        #pragma unroll
        for (int ct = 0; ct < 2; ++ct) {
          int posl = ct*16 + colr;
          uint2 u;
          u.x = pk2(lk(h2[mtp][ct][0]), lk(h2[mtp][ct][1]));
          u.y = pk2(lk(h2[mtp][ct][2]), lk(h2[mtp][ct][3]));
          *(uint2*)(PB + posl*64 + (chp2 ^ ((posl&3)<<4))) = u;
        }
      }
      bf16x8 b2[2];
      #pragma unroll
      for (int ct = 0; ct < 2; ++ct) {
        int posl = ct*16 + colr;
        b2[ct] = *(const bf16x8*)(PB + posl*64 + ((kq*16) ^ ((posl&3)<<4)));
      }
      #pragma unroll
      for (int mt = 0; mt < 8; ++mt) {
        int row = mt*16 + colr;
        bf16x8 w = WF(WC, row, 256, j*64);
        acc[mt][0] = __builtin_amdgcn_mfma_f32_16x16x32_bf16(w, b2[0], acc[mt][0], 0, 0, 0);
        acc[mt][1] = __builtin_amdgcn_mfma_f32_16x16x32_bf16(w, b2[1], acc[mt][1], 0, 0, 0);
      }
    }

    __syncthreads();
    #pragma unroll
    for (int mt = 0; mt < 8; ++mt) {
      #pragma unroll
      for (int ct = 0; ct < 2; ++ct) {
        #pragma unroll
        for (int r = 0; r < 4; ++r) {
          float v = acc[mt][ct][r];
          v = fmaxf(v, __shfl_xor(v, 1));
          v = fmaxf(v, __shfl_xor(v, 2));
          v = fmaxf(v, __shfl_xor(v, 4));
          v = fmaxf(v, __shfl_xor(v, 8));
          if (colr == 0) S.outT[mt*16 + kq*4 + r][wv*2 + ct] = v;
        }
      }
    }
    __syncthreads();
    {
      int ch = tid >> 2, p = tid & 3;
      int b = bn0 >> 13, n0 = bn0 & (N_-1);
      float4 v4 = *(const float4*)&S.outT[ch][p*4];
      *(float4*)(out + ((size_t)b*128 + ch)*N_ + n0 + p*4) = v4;
    }

    #pragma unroll
    for (int ct = 0; ct < 2; ++ct)
      #pragma unroll
      for (int ks = 0; ks < 4; ++ks)
        bx[ct][ks] = bxn[ct][ks];
  }
#undef WF
}

extern "C" void kernel_launch(void* const* d_in, const int* in_sizes, int n_in,
                              void* d_out, int out_size, void* d_ws, size_t ws_size,
                              hipStream_t stream) {
  const float* xyz     = (const float*)d_in[0];
  const float* p1_sc_w = (const float*)d_in[1];
  const float* p1_sc_b = (const float*)d_in[2];
  const float* p1_a_w  = (const float*)d_in[3];
  const float* p1_a_b  = (const float*)d_in[4];
  const float* p1_b_w  = (const float*)d_in[5];
  const float* p1_b_b  = (const float*)d_in[6];
  const float* p1_c_w  = (const float*)d_in[7];
  const float* p1_c_b  = (const float*)d_in[8];
  const float* p2_sc_w = (const float*)d_in[9];
  const float* p2_sc_b = (const float*)d_in[10];
  const float* p2_a_w  = (const float*)d_in[11];
  const float* p2_a_b  = (const float*)d_in[12];
  const float* p2_b_w  = (const float*)d_in[13];
  const float* p2_b_b  = (const float*)d_in[14];
  const float* p2_c_w  = (const float*)d_in[15];
  const float* p2_c_b  = (const float*)d_in[16];

  if (ws_size < 75497472u) return;  // need ~72 MB scratch
  char* ws = (char*)d_ws;
  float4* pts4        = (float4*)(ws);
  unsigned short* wbf = (unsigned short*)(ws + 524288);
  int* knn            = (int*)(ws + 655360);
  unsigned short* X   = (unsigned short*)(ws + 4194304);
  unsigned short* XM  = (unsigned short*)(ws + 4194304 + 67108864);
  float* out = (float*)d_out;

  k_prep<<<dim3(BN_/256), dim3(256), 0, stream>>>(xyz, pts4);
  k_wcvt<<<dim3(240), dim3(256), 0, stream>>>(p2_sc_w, p2_a_w, p2_b_w, p2_c_w,
      p1_a_w, p1_sc_w, p1_b_w, p1_c_w, wbf);
  k_knn<<<dim3(BN_/8), dim3(512), 0, stream>>>(pts4, knn);
  k_p1<<<dim3(512), dim3(512), 0, stream>>>(pts4, knn, wbf,
      p1_a_b, p1_b_b, p1_c_b, p1_sc_b, X, XM);
  k_p2<<<dim3(256), dim3(512), 0, stream>>>(X, XM, wbf,
      p2_sc_b, p2_a_b, p2_b_b, p2_c_b, out);
}

// Round 7
// 377.305 us; speedup vs baseline: 2.8604x; 1.0684x over previous
//
#include <hip/hip_runtime.h>
#include <hip/hip_bf16.h>

#define B_ 4
#define N_ 8192
#define KNN 16
#define BN_ (B_*N_)      // 32768
#define NPOS (BN_*KNN)   // 524288

typedef __attribute__((ext_vector_type(8))) short bf16x8;
typedef __attribute__((ext_vector_type(4))) float f32x4;

static __device__ __forceinline__ unsigned short f2bf(float f) {
  union { float f; unsigned u; } v; v.f = f;
  unsigned r = v.u + 0x7fff + ((v.u >> 16) & 1);
  return (unsigned short)(r >> 16);
}
static __device__ __forceinline__ float lk(float x) { return x >= 0.f ? x : 0.2f*x; }
static __device__ __forceinline__ unsigned pk2(float a, float b) {
  return (unsigned)f2bf(a) | ((unsigned)f2bf(b) << 16);
}

// ---------------- prep: pts4 = (x,y,z,|p|^2) ----------------
__global__ void k_prep(const float* __restrict__ xyz, float4* __restrict__ pts4) {
  int i = blockIdx.x * 256 + threadIdx.x;
  if (i >= BN_) return;
  int b = i >> 13, n = i & (N_-1);
  const float* p = xyz + b*3*N_;
  float x = p[n], y = p[N_+n], z = p[2*N_+n];
  float xx = fmaf(z, z, fmaf(y, y, x*x));
  pts4[i] = make_float4(x, y, z, xx);
}

// ------- convert ALL weights to bf16, PRE-SWIZZLED LDS images -------
__global__ void k_wcvt(const float* __restrict__ w_sc, const float* __restrict__ w_a,
                       const float* __restrict__ w_b, const float* __restrict__ w_c,
                       const float* __restrict__ p1a, const float* __restrict__ p1sc,
                       const float* __restrict__ p1b, const float* __restrict__ p1c,
                       unsigned short* __restrict__ out) {
  int i = blockIdx.x*256 + threadIdx.x;
  if (i >= 61440) return;
  if (i < 49152) {
    int x = i*2;                            // byte offset in p2 image
    const float* w; int base, K2;
    if (x < 32768)      { w = w_sc; base = 0;     K2 = 256; }
    else if (x < 49152) { w = w_a;  base = 32768; K2 = 256; }
    else if (x < 65536) { w = w_b;  base = 49152; K2 = 128; }
    else                { w = w_c;  base = 65536; K2 = 256; }
    int off = x - base;
    int row = off / K2;
    int colb = (off & (K2-1)) ^ ((row & 7) << 4);
    int k = colb >> 1;
    out[i] = f2bf(w[row*(K2 >> 1) + k]);
  } else {
    int e = i - 49152;                      // 0..12287
    float val; int byteoff;
    if (e < 2048) {               // Wa 64x32 (64B rows)
      int row = e >> 5, k = e & 31;
      val = (k < 10) ? p1a[row*10 + k] : 0.f;
      byteoff = row*64 + ((2*k) ^ ((row & 3) << 4));
    } else if (e < 4096) {        // Wsc 64x32
      int le = e - 2048, row = le >> 5, k = le & 31;
      val = (k < 10) ? p1sc[row*10 + k] : 0.f;
      byteoff = 4096 + row*64 + ((2*k) ^ ((row & 3) << 4));
    } else if (e < 8192) {        // Wb 64x64 (128B rows)
      int le = e - 4096, row = le >> 6, k = le & 63;
      val = p1b[row*64 + k];
      byteoff = 8192 + row*128 + ((2*k) ^ ((row & 7) << 4));
    } else {                      // Wc 64x64
      int le = e - 8192, row = le >> 6, k = le & 63;
      val = p1c[row*64 + k];
      byteoff = 16384 + row*128 + ((2*k) ^ ((row & 7) << 4));
    }
    out[49152 + (byteoff >> 1)] = f2bf(val);
  }
}

// ---------------- KNN v4: batched scan (4 groups pipelined) + ballot-append ----------------
// u64 key = (f32bits(d2) << 32) | idx -> ascending u64 == lexicographic (d2, idx).
static __device__ __forceinline__ unsigned long long bitonic64(
    unsigned long long key, int lane) {
  #pragma unroll
  for (int size = 2; size <= 64; size <<= 1) {
    #pragma unroll
    for (int stride = size >> 1; stride >= 1; stride >>= 1) {
      unsigned long long ok = __shfl_xor((long long)key, stride);
      bool up = ((lane & size) == 0);
      bool keepmin = (((lane & stride) == 0) == up);
      bool oless = ok < key;
      if (oless == keepmin) key = ok;
    }
  }
  return key;
}

template<int U>
static __device__ __forceinline__ void scan_groups(
    const float4* __restrict__ cand, int itbase, int ch,
    float4 me, int lane,
    unsigned long long* __restrict__ bw,
    unsigned long long& topk, float& rhs, int& cnt) {
  // phase 1: U independent loads + screen values, NO control flow between them
  float s[U]; int cid[U];
  #pragma unroll
  for (int u = 0; u < U; ++u) {
    int ci = (itbase + u)*64 + lane;
    float4 c = cand[ci];
    float dot = fmaf(me.z, c.z, fmaf(me.y, c.y, me.x*c.x));
    s[u] = fmaf(-2.0f, dot, c.w);          // d2 = me.w + s
    cid[u] = ch*2048 + ci;
  }
  // phase 2: ballot checks; appends rare, compactions rarer
  #pragma unroll
  for (int u = 0; u < U; ++u) {
    unsigned long long m = __ballot(s[u] < rhs);
    if (m) {
      int prefix = __builtin_amdgcn_mbcnt_hi((unsigned)(m >> 32),
                    __builtin_amdgcn_mbcnt_lo((unsigned)m, 0));
      if (s[u] < rhs) {
        float d2 = me.w + s[u];
        bw[cnt + prefix] =
          ((unsigned long long)__float_as_uint(d2) << 32) | (unsigned)cid[u];
      }
      cnt += __popcll(m);
      if (cnt >= 48) {      // keep invariant: cnt<48 before any append batch (buf 112)
        int base = 0;
        while (cnt > 0) {
          int c2 = cnt > 48 ? 48 : cnt;
          unsigned long long e = (lane < 16) ? topk
            : ((lane - 16) < c2 ? bw[base + lane - 16] : ~0ull);
          topk = bitonic64(e, lane);
          base += c2; cnt -= c2;
        }
        unsigned long long k15 = __shfl((long long)topk, 15);
        rhs = __uint_as_float((unsigned)(k15 >> 32)) - me.w;
      }
    }
  }
}

__global__ __launch_bounds__(512) void k_knn(const float4* __restrict__ pts4,
                                             int* __restrict__ knn) {
  __shared__ float4 cand[2048];
  __shared__ unsigned long long buf[8][112];
  const int lane = threadIdx.x & 63;
  const int wv   = threadIdx.x >> 6;
  const int q = blockIdx.x * 8 + wv;
  const int b = q >> 13;
  const int n = q & (N_-1);
  const float4* __restrict__ P = pts4 + (b << 13);
  float4 me = P[n];

  unsigned long long topk = ~0ull;   // lanes 0..15: sorted top-16 keys
  float rhs = __builtin_inff();      // worst - me.w
  int cnt = 0;
  unsigned long long* __restrict__ bw = buf[wv];

  for (int ch = 0; ch < 4; ++ch) {
    __syncthreads();
    #pragma unroll
    for (int t = 0; t < 4; ++t)
      cand[t*512 + threadIdx.x] = P[ch*2048 + t*512 + threadIdx.x];
    __syncthreads();

    if (ch == 0) {
      // warm start: exact top-16 of candidates 0..63
      float4 c = cand[lane];
      float dot = fmaf(me.z, c.z, fmaf(me.y, c.y, me.x*c.x));
      float d2 = (me.w + c.w) - 2.0f*dot;
      unsigned long long key =
        ((unsigned long long)__float_as_uint(d2) << 32) | (unsigned)lane;
      topk = bitonic64(key, lane);
      unsigned long long k15 = __shfl((long long)topk, 15);
      rhs = __uint_as_float((unsigned)(k15 >> 32)) - me.w;
      scan_groups<3>(cand, 1, 0, me, lane, bw, topk, rhs, cnt);
      #pragma unroll 1
      for (int it = 4; it < 32; it += 4)
        scan_groups<4>(cand, it, 0, me, lane, bw, topk, rhs, cnt);
    } else {
      #pragma unroll 1
      for (int it = 0; it < 32; it += 4)
        scan_groups<4>(cand, it, ch, me, lane, bw, topk, rhs, cnt);
    }
  }
  // final drain
  {
    int base = 0;
    while (cnt > 0) {
      int c2 = cnt > 48 ? 48 : cnt;
      unsigned long long e = (lane < 16) ? topk
        : ((lane - 16) < c2 ? bw[base + lane - 16] : ~0ull);
      topk = bitonic64(e, lane);
      base += c2; cnt -= c2;
    }
  }
  if (lane < 16) knn[(q << 4) + lane] = (int)(unsigned)(topk & 0xffffffffu);
}

// ---------------- phase-1 conv-res on MFMA, PERSISTENT (4 tiles/block) ----------------
__global__ __launch_bounds__(512, 4) void k_p1(
    const float4* __restrict__ pts4, const int* __restrict__ knn,
    const unsigned short* __restrict__ wbf,
    const float* __restrict__ a_b, const float* __restrict__ b_b,
    const float* __restrict__ c_b, const float* __restrict__ sc_b,
    unsigned short* __restrict__ X, unsigned short* __restrict__ XM) {
  __shared__ __align__(16) unsigned short Ws1[12288];  // 24 KB swizzled weights
  __shared__ __align__(16) unsigned short Fs[8192];    // 16 KB features
  __shared__ __align__(16) unsigned short Hr[16384];   // 32 KB wave H regions
  const int tid = threadIdx.x;
  const int lane = tid & 63, wv = tid >> 6;
  const int colr = lane & 15, kq = lane >> 4;

  #pragma unroll
  for (int j = 0; j < 3; ++j) {
    int c = j*512 + tid;
    ((uint4*)Ws1)[c] = ((const uint4*)(wbf + 49152))[c];
  }
  const char* WS = (const char*)Ws1;
  char* H = (char*)Hr + wv*4096;

  for (int tile = 0; tile < 4; ++tile) {
    const int bn0 = (blockIdx.x*4 + tile) * 16;
    __syncthreads();
    if (tid < 256) {
      int bnl = tid >> 4, kk = tid & 15;
      int bn = bn0 + bnl;
      int b = bn >> 13;
      float4 cp = pts4[bn];
      int nid = knn[bn*16 + kk];
      float4 np = pts4[(b << 13) + nid];
      float rx = np.x - cp.x, ry = np.y - cp.y, rz = np.z - cp.z;
      float dist = sqrtf(fmaf(rz, rz, fmaf(ry, ry, rx*rx)) + 1e-12f);
      unsigned short row[32];
      row[0]=f2bf(cp.x); row[1]=f2bf(cp.y); row[2]=f2bf(cp.z);
      row[3]=f2bf(np.x); row[4]=f2bf(np.y); row[5]=f2bf(np.z);
      row[6]=f2bf(rx);   row[7]=f2bf(ry);   row[8]=f2bf(rz);   row[9]=f2bf(dist);
      #pragma unroll
      for (int j = 10; j < 32; ++j) row[j] = 0;
      int wvp = tid >> 5, posl = tid & 31;
      char* dst = (char*)Fs + wvp*2048 + posl*64;
      #pragma unroll
      for (int c = 0; c < 4; ++c)
        *(uint4*)(dst + ((c*16) ^ ((posl&3)<<4))) = *(const uint4*)(row + c*8);
    }
    __syncthreads();

    bf16x8 bfr[2];
    #pragma unroll
    for (int ct = 0; ct < 2; ++ct) {
      int posl = ct*16 + colr;
      bfr[ct] = *(const bf16x8*)((const char*)Fs + wv*2048 + posl*64 + ((kq*16) ^ ((posl&3)<<4)));
    }

    f32x4 acc[4][2];
    #pragma unroll
    for (int mt = 0; mt < 4; ++mt) {
      int r0 = mt*16 + kq*4;
      #pragma unroll
      for (int r = 0; r < 4; ++r) {
        float bia = c_b[r0+r] + sc_b[r0+r];
        acc[mt][0][r] = bia; acc[mt][1][r] = bia;
      }
    }
    #pragma unroll
    for (int mt = 0; mt < 4; ++mt) {
      int row = mt*16 + colr;
      bf16x8 w = *(const bf16x8*)(WS + 4096 + row*64 + ((kq*16) ^ ((row&3)<<4)));
      acc[mt][0] = __builtin_amdgcn_mfma_f32_16x16x32_bf16(w, bfr[0], acc[mt][0], 0, 0, 0);
      acc[mt][1] = __builtin_amdgcn_mfma_f32_16x16x32_bf16(w, bfr[1], acc[mt][1], 0, 0, 0);
    }

    f32x4 ha[4][2];
    #pragma unroll
    for (int mt = 0; mt < 4; ++mt) {
      int r0 = mt*16 + kq*4;
      #pragma unroll
      for (int r = 0; r < 4; ++r) { ha[mt][0][r] = a_b[r0+r]; ha[mt][1][r] = a_b[r0+r]; }
    }
    #pragma unroll
    for (int mt = 0; mt < 4; ++mt) {
      int row = mt*16 + colr;
      bf16x8 w = *(const bf16x8*)(WS + row*64 + ((kq*16) ^ ((row&3)<<4)));
      ha[mt][0] = __builtin_amdgcn_mfma_f32_16x16x32_bf16(w, bfr[0], ha[mt][0], 0, 0, 0);
      ha[mt][1] = __builtin_amdgcn_mfma_f32_16x16x32_bf16(w, bfr[1], ha[mt][1], 0, 0, 0);
    }

    #pragma unroll
    for (int mt = 0; mt < 4; ++mt) {
      int ch2 = (mt*16 + kq*4) * 2;
      #pragma unroll
      for (int ct = 0; ct < 2; ++ct) {
        int posl = ct*16 + colr;
        uint2 u;
        u.x = pk2(lk(ha[mt][ct][0]), lk(ha[mt][ct][1]));
        u.y = pk2(lk(ha[mt][ct][2]), lk(ha[mt][ct][3]));
        *(uint2*)(H + posl*128 + (ch2 ^ ((posl&7)<<4))) = u;
      }
    }
    bf16x8 bh[2][2];
    #pragma unroll
    for (int ct = 0; ct < 2; ++ct) {
      int posl = ct*16 + colr;
      #pragma unroll
      for (int k2 = 0; k2 < 2; ++k2)
        bh[ct][k2] = *(const bf16x8*)(H + posl*128 + ((k2*64 + kq*16) ^ ((posl&7)<<4)));
    }

    #pragma unroll
    for (int jj = 0; jj < 2; ++jj) {
      f32x4 h2[2][2];
      #pragma unroll
      for (int mtp = 0; mtp < 2; ++mtp) {
        int r0 = (jj*2 + mtp)*16 + kq*4;
        #pragma unroll
        for (int r = 0; r < 4; ++r) { h2[mtp][0][r] = b_b[r0+r]; h2[mtp][1][r] = b_b[r0+r]; }
      }
      #pragma unroll
      for (int mtp = 0; mtp < 2; ++mtp) {
        int row = (jj*2 + mtp)*16 + colr;
        #pragma unroll
        for (int k2 = 0; k2 < 2; ++k2) {
          bf16x8 w = *(const bf16x8*)(WS + 8192 + row*128 + ((k2*64 + kq*16) ^ ((row&7)<<4)));
          h2[mtp][0] = __builtin_amdgcn_mfma_f32_16x16x32_bf16(w, bh[0][k2], h2[mtp][0], 0, 0, 0);
          h2[mtp][1] = __builtin_amdgcn_mfma_f32_16x16x32_bf16(w, bh[1][k2], h2[mtp][1], 0, 0, 0);
        }
      }
      #pragma unroll
      for (int mtp = 0; mtp < 2; ++mtp) {
        int ch2 = ((jj*2 + mtp)*16 + kq*4) * 2;
        #pragma unroll
        for (int ct = 0; ct < 2; ++ct) {
          int posl = ct*16 + colr;
          uint2 u;
          u.x = pk2(lk(h2[mtp][ct][0]), lk(h2[mtp][ct][1]));
          u.y = pk2(lk(h2[mtp][ct][2]), lk(h2[mtp][ct][3]));
          *(uint2*)(H + posl*128 + (ch2 ^ ((posl&7)<<4))) = u;
        }
      }
      bf16x8 b2[2];
      #pragma unroll
      for (int ct = 0; ct < 2; ++ct) {
        int posl = ct*16 + colr;
        b2[ct] = *(const bf16x8*)(H + posl*128 + ((jj*64 + kq*16) ^ ((posl&7)<<4)));
      }
      #pragma unroll
      for (int mt = 0; mt < 4; ++mt) {
        int row = mt*16 + colr;
        bf16x8 w = *(const bf16x8*)(WS + 16384 + row*128 + ((jj*64 + kq*16) ^ ((row&7)<<4)));
        acc[mt][0] = __builtin_amdgcn_mfma_f32_16x16x32_bf16(w, b2[0], acc[mt][0], 0, 0, 0);
        acc[mt][1] = __builtin_amdgcn_mfma_f32_16x16x32_bf16(w, b2[1], acc[mt][1], 0, 0, 0);
      }
    }

    #pragma unroll
    for (int ct = 0; ct < 2; ++ct) {
      int bn = bn0 + wv*2 + ct;
      #pragma unroll
      for (int mt = 0; mt < 4; ++mt) {
        int ch0 = mt*16 + kq*4;
        uint2 u;
        u.x = pk2(acc[mt][ct][0], acc[mt][ct][1]);
        u.y = pk2(acc[mt][ct][2], acc[mt][ct][3]);
        *(uint2*)(X + ((size_t)(bn*16 + colr))*64 + ch0) = u;
        float m[4];
        #pragma unroll
        for (int r = 0; r < 4; ++r) {
          float v = acc[mt][ct][r];
          v = fmaxf(v, __shfl_xor(v, 1));
          v = fmaxf(v, __shfl_xor(v, 2));
          v = fmaxf(v, __shfl_xor(v, 4));
          v = fmaxf(v, __shfl_xor(v, 8));
          m[r] = v;
        }
        if (colr == 0) {
          uint2 um; um.x = pk2(m[0], m[1]); um.y = pk2(m[2], m[3]);
          *(uint2*)(XM + (size_t)bn*64 + ch0) = um;
        }
      }
    }
  }
}

// ---------------- phase-2 fused MFMA chain, PERSISTENT (8 tiles/block) ----------------
struct P2Shared {
  unsigned short Ws[49152];
  unsigned short Hr[8][2048];
  float outT[128][16];
};

static __device__ __forceinline__ void p2_loadbx(
    bf16x8 (&dst)[2][4], const unsigned short* __restrict__ X,
    const unsigned short* __restrict__ XM, int bn0, int wv, int colr, int kq) {
  #pragma unroll
  for (int ct = 0; ct < 2; ++ct) {
    int bn = bn0 + wv*2 + ct;
    const unsigned short* xr = X + ((size_t)bn*16 + colr)*64 + kq*8;
    dst[ct][0] = *(const bf16x8*)(xr);
    dst[ct][1] = *(const bf16x8*)(xr + 32);
    const unsigned short* mr = XM + (size_t)bn*64 + kq*8;
    dst[ct][2] = *(const bf16x8*)(mr);
    dst[ct][3] = *(const bf16x8*)(mr + 32);
  }
}

__global__ __launch_bounds__(512, 2) void k_p2(
    const unsigned short* __restrict__ X, const unsigned short* __restrict__ XM,
    const unsigned short* __restrict__ wbf,
    const float* __restrict__ sc_b, const float* __restrict__ a_b,
    const float* __restrict__ b_b, const float* __restrict__ c_b,
    float* __restrict__ out) {
  __shared__ __align__(16) P2Shared S;
  const int tid = threadIdx.x;
  const int lane = tid & 63, wv = tid >> 6;
  const int colr = lane & 15, kq = lane >> 4;

  #pragma unroll
  for (int it = 0; it < 12; ++it) {
    int c = it*512 + tid;
    *(uint4*)((char*)S.Ws + c*16) = *(const uint4*)((const char*)wbf + c*16);
  }

  const char* WSC = (const char*)S.Ws;
  const char* WA  = (const char*)(S.Ws + 16384);
  const char* WB  = (const char*)(S.Ws + 24576);
  const char* WC  = (const char*)(S.Ws + 32768);
  char* H = (char*)S.Hr[wv];

#define WF(base, row, K2, ksbyte) \
  (*(const bf16x8*)((base) + (row)*(K2) + ((((ksbyte) + kq*16)) ^ (((row)&7)<<4))))

  bf16x8 bx[2][4], bxn[2][4];
  p2_loadbx(bx, X, XM, blockIdx.x*8*16, wv, colr, kq);
  __syncthreads();

  for (int t = 0; t < 8; ++t) {
    const int bn0 = (blockIdx.x*8 + t) * 16;

    f32x4 acc[8][2];
    #pragma unroll
    for (int mt = 0; mt < 8; ++mt) {
      int r0 = mt*16 + kq*4;
      #pragma unroll
      for (int r = 0; r < 4; ++r) {
        float bia = c_b[r0+r] + sc_b[r0+r];
        acc[mt][0][r] = bia; acc[mt][1][r] = bia;
      }
    }
    #pragma unroll
    for (int mt = 0; mt < 8; ++mt) {
      int row = mt*16 + colr;
      #pragma unroll
      for (int ks = 0; ks < 4; ++ks) {
        bf16x8 w = WF(WSC, row, 256, ks*64);
        acc[mt][0] = __builtin_amdgcn_mfma_f32_16x16x32_bf16(w, bx[0][ks], acc[mt][0], 0, 0, 0);
        acc[mt][1] = __builtin_amdgcn_mfma_f32_16x16x32_bf16(w, bx[1][ks], acc[mt][1], 0, 0, 0);
      }
    }

    f32x4 ha[4][2];
    #pragma unroll
    for (int mt = 0; mt < 4; ++mt) {
      int r0 = mt*16 + kq*4;
      #pragma unroll
      for (int r = 0; r < 4; ++r) { ha[mt][0][r] = a_b[r0+r]; ha[mt][1][r] = a_b[r0+r]; }
    }
    #pragma unroll
    for (int mt = 0; mt < 4; ++mt) {
      int row = mt*16 + colr;
      #pragma unroll
      for (int ks = 0; ks < 4; ++ks) {
        bf16x8 w = WF(WA, row, 256, ks*64);
        ha[mt][0] = __builtin_amdgcn_mfma_f32_16x16x32_bf16(w, bx[0][ks], ha[mt][0], 0, 0, 0);
        ha[mt][1] = __builtin_amdgcn_mfma_f32_16x16x32_bf16(w, bx[1][ks], ha[mt][1], 0, 0, 0);
      }
    }

    {
      int tn = (t < 7) ? (t + 1) : 7;
      p2_loadbx(bxn, X, XM, (blockIdx.x*8 + tn) * 16, wv, colr, kq);
    }

    #pragma unroll
    for (int mt = 0; mt < 4; ++mt) {
      int ch2 = (mt*16 + kq*4) * 2;
      #pragma unroll
      for (int ct = 0; ct < 2; ++ct) {
        int posl = ct*16 + colr;
        uint2 u;
        u.x = pk2(lk(ha[mt][ct][0]), lk(ha[mt][ct][1]));
        u.y = pk2(lk(ha[mt][ct][2]), lk(ha[mt][ct][3]));
        *(uint2*)(H + posl*128 + (ch2 ^ ((posl&7)<<4))) = u;
      }
    }
    bf16x8 bh[2][2];
    #pragma unroll
    for (int ct = 0; ct < 2; ++ct) {
      int posl = ct*16 + colr;
      #pragma unroll
      for (int k2 = 0; k2 < 2; ++k2)
        bh[ct][k2] = *(const bf16x8*)(H + posl*128 + ((k2*64 + kq*16) ^ ((posl&7)<<4)));
    }

    #pragma unroll
    for (int j = 0; j < 4; ++j) {
      f32x4 h2[2][2];
      #pragma unroll
      for (int mtp = 0; mtp < 2; ++mtp) {
        int r0 = (2*j + mtp)*16 + kq*4;
        #pragma unroll
        for (int r = 0; r < 4; ++r) { h2[mtp][0][r] = b_b[r0+r]; h2[mtp][1][r] = b_b[r0+r]; }
      }
      #pragma unroll
      for (int mtp = 0; mtp < 2; ++mtp) {
        int row = (2*j + mtp)*16 + colr;
        #pragma unroll
        for (int k2 = 0; k2 < 2; ++k2) {
          bf16x8 w = WF(WB, row, 128, k2*64);
          h2[mtp][0] = __builtin_amdgcn_mfma_f32_16x16x32_bf16(w, bh[0][k2], h2[mtp][0], 0, 0, 0);
          h2[mtp][1] = __builtin_amdgcn_mfma_f32_16x16x32_bf16(w, bh[1][k2], h2[mtp][1], 0, 0, 0);
        }
      }
      char* PB = H + (j & 1)*2048;
      #pragma unroll
      for (int mtp = 0; mtp < 2; ++mtp) {
        int chp2 = (mtp*16 + kq*4) * 2;
        #pragma unroll
        for (int ct = 0; ct < 2; ++ct) {
          int posl = ct*16 + colr;
          uint2 u;
          u.x = pk2(lk(h2[mtp][ct][0]), lk(h2[mtp][ct][1]));
          u.y = pk2(lk(h2[mtp][ct][2]), lk(h2[mtp][ct][3]));
          *(uint2*)(PB + posl*64 + (chp2 ^ ((posl&3)<<4))) = u;
        }
      }
      bf16x8 b2[2];
      #pragma unroll
      for (int ct = 0; ct < 2; ++ct) {
        int posl = ct*16 + colr;
        b2[ct] = *(const bf16x8*)(PB + posl*64 + ((kq*16) ^ ((posl&3)<<4)));
      }
      #pragma unroll
      for (int mt = 0; mt < 8; ++mt) {
        int row = mt*16 + colr;
        bf16x8 w = WF(WC, row, 256, j*64);
        acc[mt][0] = __builtin_amdgcn_mfma_f32_16x16x32_bf16(w, b2[0], acc[mt][0], 0, 0, 0);
        acc[mt][1] = __builtin_amdgcn_mfma_f32_16x16x32_bf16(w, b2[1], acc[mt][1], 0, 0, 0);
      }
    }

    __syncthreads();
    #pragma unroll
    for (int mt = 0; mt < 8; ++mt) {
      #pragma unroll
      for (int ct = 0; ct < 2; ++ct) {
        #pragma unroll
        for (int r = 0; r < 4; ++r) {
          float v = acc[mt][ct][r];
          v = fmaxf(v, __shfl_xor(v, 1));
          v = fmaxf(v, __shfl_xor(v, 2));
          v = fmaxf(v, __shfl_xor(v, 4));
          v = fmaxf(v, __shfl_xor(v, 8));
          if (colr == 0) S.outT[mt*16 + kq*4 + r][wv*2 + ct] = v;
        }
      }
    }
    __syncthreads();
    {
      int ch = tid >> 2, p = tid & 3;
      int b = bn0 >> 13, n0 = bn0 & (N_-1);
      float4 v4 = *(const float4*)&S.outT[ch][p*4];
      *(float4*)(out + ((size_t)b*128 + ch)*N_ + n0 + p*4) = v4;
    }

    #pragma unroll
    for (int ct = 0; ct < 2; ++ct)
      #pragma unroll
      for (int ks = 0; ks < 4; ++ks)
        bx[ct][ks] = bxn[ct][ks];
  }
#undef WF
}

extern "C" void kernel_launch(void* const* d_in, const int* in_sizes, int n_in,
                              void* d_out, int out_size, void* d_ws, size_t ws_size,
                              hipStream_t stream) {
  const float* xyz     = (const float*)d_in[0];
  const float* p1_sc_w = (const float*)d_in[1];
  const float* p1_sc_b = (const float*)d_in[2];
  const float* p1_a_w  = (const float*)d_in[3];
  const float* p1_a_b  = (const float*)d_in[4];
  const float* p1_b_w  = (const float*)d_in[5];
  const float* p1_b_b  = (const float*)d_in[6];
  const float* p1_c_w  = (const float*)d_in[7];
  const float* p1_c_b  = (const float*)d_in[8];
  const float* p2_sc_w = (const float*)d_in[9];
  const float* p2_sc_b = (const float*)d_in[10];
  const float* p2_a_w  = (const float*)d_in[11];
  const float* p2_a_b  = (const float*)d_in[12];
  const float* p2_b_w  = (const float*)d_in[13];
  const float* p2_b_b  = (const float*)d_in[14];
  const float* p2_c_w  = (const float*)d_in[15];
  const float* p2_c_b  = (const float*)d_in[16];

  if (ws_size < 75497472u) return;  // need ~72 MB scratch
  char* ws = (char*)d_ws;
  float4* pts4        = (float4*)(ws);
  unsigned short* wbf = (unsigned short*)(ws + 524288);
  int* knn            = (int*)(ws + 655360);
  unsigned short* X   = (unsigned short*)(ws + 4194304);
  unsigned short* XM  = (unsigned short*)(ws + 4194304 + 67108864);
  float* out = (float*)d_out;

  k_prep<<<dim3(BN_/256), dim3(256), 0, stream>>>(xyz, pts4);
  k_wcvt<<<dim3(240), dim3(256), 0, stream>>>(p2_sc_w, p2_a_w, p2_b_w, p2_c_w,
      p1_a_w, p1_sc_w, p1_b_w, p1_c_w, wbf);
  k_knn<<<dim3(BN_/8), dim3(512), 0, stream>>>(pts4, knn);
  k_p1<<<dim3(512), dim3(512), 0, stream>>>(pts4, knn, wbf,
      p1_a_b, p1_b_b, p1_c_b, p1_sc_b, X, XM);
  k_p2<<<dim3(256), dim3(512), 0, stream>>>(X, XM, wbf,
      p2_sc_b, p2_a_b, p2_b_b, p2_c_b, out);
}